// Round 7
// baseline (289.278 us; speedup 1.0000x reference)
//
#include <hip/hip_runtime.h>
#include <hip/hip_fp16.h>
#include <math.h>

#define NF   128
#define HID  16
#define NPB  128          // nodes per bucket (dst >> 7)
#define CAP  768          // records per (xcd, bucket) cell; mean 511
#define NXCD 8
#define SMAX (NXCD * CAP) // max records per bucket in LDS sort (6144)
#define OVF_CAP 262144    // statistically-unreachable overflow list
#define KMAX 1024         // max buckets (N <= 131072)
#define CH   2048         // edges per block in scatter_bin (8/thread, reg-cached)
#define GBLK 4            // gather blocks per bucket (R7)
#define GNODES (NPB/GBLK) // 32 nodes per gather block

typedef _Float16 half8 __attribute__((ext_vector_type(8)));
typedef _Float16 half4 __attribute__((ext_vector_type(4)));
typedef float    floatx4 __attribute__((ext_vector_type(4)));

// ---------------------------------------------------------------------------
__global__ void zero_kernel(int* __restrict__ ptr, int n) {
    int i = blockIdx.x * blockDim.x + threadIdx.x;
    if (i < n) ptr[i] = 0;
}

// ---------------------------------------------------------------------------
// Block-chunked two-pass binning: LDS histogram -> one XCD-local L2 atomic
// per touched bucket -> private contiguous range fill.
// Record = (dst & 127) << 17 | src   (src < 2^17).
__global__ __launch_bounds__(256) void scatter_bin_kernel(
    const int* __restrict__ src, const int* __restrict__ dst,
    int* __restrict__ cursor, int* __restrict__ recs,
    int* __restrict__ ovf_cnt, int2* __restrict__ ovf, int E, int K)
{
    __shared__ int cnt[KMAX];
    __shared__ int resbase[KMAX];
    __shared__ int cur[KMAX];

    int tid  = threadIdx.x;
    int base = blockIdx.x * CH;

    for (int b = tid; b < K; b += 256) cnt[b] = 0;
    __syncthreads();

    int ebase = base + tid * 8;
    int4 da = {0,0,0,0}, db = {0,0,0,0}, sa = {0,0,0,0}, sb = {0,0,0,0};
    if (ebase + 8 <= E) {
        da = ((const int4*)(dst + ebase))[0];
        db = ((const int4*)(dst + ebase))[1];
        sa = ((const int4*)(src + ebase))[0];
        sb = ((const int4*)(src + ebase))[1];
    } else if (ebase < E) {
        int m = E - ebase;
        if (m > 0) { da.x = dst[ebase+0]; sa.x = src[ebase+0]; }
        if (m > 1) { da.y = dst[ebase+1]; sa.y = src[ebase+1]; }
        if (m > 2) { da.z = dst[ebase+2]; sa.z = src[ebase+2]; }
        if (m > 3) { da.w = dst[ebase+3]; sa.w = src[ebase+3]; }
        if (m > 4) { db.x = dst[ebase+4]; sb.x = src[ebase+4]; }
        if (m > 5) { db.y = dst[ebase+5]; sb.y = src[ebase+5]; }
        if (m > 6) { db.z = dst[ebase+6]; sb.z = src[ebase+6]; }
    }
    int ne = E - ebase; ne = ne < 0 ? 0 : (ne > 8 ? 8 : ne);
    int d[8] = {da.x, da.y, da.z, da.w, db.x, db.y, db.z, db.w};
    int s[8] = {sa.x, sa.y, sa.z, sa.w, sb.x, sb.y, sb.z, sb.w};

    #pragma unroll
    for (int i = 0; i < 8; ++i)
        if (i < ne) atomicAdd(&cnt[((unsigned)d[i]) >> 7], 1);
    __syncthreads();

    int xcd;
    asm volatile("s_getreg_b32 %0, hwreg(HW_REG_XCC_ID)" : "=s"(xcd));
    xcd &= 7;

    for (int b = tid; b < K; b += 256) {
        int c = cnt[b];
        cur[b] = 0;
        if (c > 0)
            resbase[b] = __hip_atomic_fetch_add(&cursor[xcd * K + b], c,
                                                __ATOMIC_RELAXED,
                                                __HIP_MEMORY_SCOPE_WORKGROUP);
    }
    __syncthreads();

    #pragma unroll
    for (int i = 0; i < 8; ++i) {
        if (i >= ne) break;
        int b = ((unsigned)d[i]) >> 7;
        int idx  = atomicAdd(&cur[b], 1);          // LDS
        int slot = resbase[b] + idx;
        if (slot < CAP) {
            recs[((size_t)(xcd * K + b)) * CAP + slot] = ((d[i] & 127) << 17) | s[i];
        } else {
            int op = atomicAdd(ovf_cnt, 1);        // device scope; ~never
            if (op < OVF_CAP) ovf[op] = make_int2(d[i], s[i]);
        }
    }
}

// ---------------------------------------------------------------------------
// R3: MFMA gemm1. One wave = 16-node tile. A-frag = W^T in registers as
// fp16 hi/lo split pairs. B-frag = 32B of the lane's x row per K-step.
// C = P^T: lane(quad,n) holds features quad*4..+3 of node n -> 8B stores.
__global__ __launch_bounds__(256, 4) void gemm1_kernel(
    const float* __restrict__ x, const float* __restrict__ wl,
    const float* __restrict__ wr, __half* __restrict__ p,
    __half* __restrict__ q, int N, int ntiles)
{
    int lane   = threadIdx.x & 63;
    int wave   = (blockIdx.x * blockDim.x + threadIdx.x) >> 6;
    int nwaves = (gridDim.x * blockDim.x) >> 6;

    int m  = lane & 15;   // A row (feature) / B col (node) / C col (node)
    int qd = lane >> 4;   // quad

    half8 wlh[4], wll[4], wrh[4], wrl[4];
    #pragma unroll
    for (int kk = 0; kk < 4; ++kk) {
        #pragma unroll
        for (int j = 0; j < 8; ++j) {
            int k = kk * 32 + qd * 8 + j;
            float a = wl[k * HID + m];
            _Float16 ah = (_Float16)a;
            wlh[kk][j] = ah;
            wll[kk][j] = (_Float16)(a - (float)ah);
            float b = wr[k * HID + m];
            _Float16 bh = (_Float16)b;
            wrh[kk][j] = bh;
            wrl[kk][j] = (_Float16)(b - (float)bh);
        }
    }

    for (int t = wave; t < ntiles; t += nwaves) {
        int node = t * 16 + m;
        int nc   = node < N ? node : N - 1;
        const float4* xr = (const float4*)(x + (size_t)nc * NF);

        floatx4 accl = {0.f, 0.f, 0.f, 0.f};
        floatx4 accr = {0.f, 0.f, 0.f, 0.f};

        #pragma unroll
        for (int kk = 0; kk < 4; ++kk) {
            float4 v0 = xr[kk * 8 + qd * 2 + 0];
            float4 v1 = xr[kk * 8 + qd * 2 + 1];
            float xs[8] = {v0.x, v0.y, v0.z, v0.w, v1.x, v1.y, v1.z, v1.w};
            half8 xh, xlo;
            #pragma unroll
            for (int j = 0; j < 8; ++j) {
                _Float16 hh = (_Float16)xs[j];
                xh[j]  = hh;
                xlo[j] = (_Float16)(xs[j] - (float)hh);
            }
            accl = __builtin_amdgcn_mfma_f32_16x16x32_f16(wlh[kk], xh,  accl, 0, 0, 0);
            accr = __builtin_amdgcn_mfma_f32_16x16x32_f16(wrh[kk], xh,  accr, 0, 0, 0);
            accl = __builtin_amdgcn_mfma_f32_16x16x32_f16(wll[kk], xh,  accl, 0, 0, 0);
            accr = __builtin_amdgcn_mfma_f32_16x16x32_f16(wrl[kk], xh,  accr, 0, 0, 0);
            accl = __builtin_amdgcn_mfma_f32_16x16x32_f16(wlh[kk], xlo, accl, 0, 0, 0);
            accr = __builtin_amdgcn_mfma_f32_16x16x32_f16(wrh[kk], xlo, accr, 0, 0, 0);
        }

        if (node < N) {
            float2 pv, qv;
            *(__half2*)&pv.x = __floats2half2_rn(accl[0], accl[1]);
            *(__half2*)&pv.y = __floats2half2_rn(accl[2], accl[3]);
            *(__half2*)&qv.x = __floats2half2_rn(accr[0], accr[1]);
            *(__half2*)&qv.y = __floats2half2_rn(accr[2], accr[3]);
            *(float2*)(p + (size_t)node * HID + qd * 4) = pv;
            *(float2*)(q + (size_t)node * HID + qd * 4) = qv;
        }
    }
}

// ---------------------------------------------------------------------------
// Accumulate helper: 8 features from a 16B half-row.
#define ACC8(raw)                                                      \
    {                                                                  \
        float2 v0 = __half22float2(*(const __half2*)&(raw).x);         \
        float2 v1 = __half22float2(*(const __half2*)&(raw).y);         \
        float2 v2 = __half22float2(*(const __half2*)&(raw).z);         \
        float2 v3 = __half22float2(*(const __half2*)&(raw).w);         \
        a0 += v0.x; a1 += v0.y; a2 += v1.x; a3 += v1.y;                \
        a4 += v2.x; a5 += v2.y; a6 += v3.x; a7 += v3.y;                \
    }

// R7: stride-4 (part 0..3) 8-deep unrolled gather-accumulate over the
// LDS-relative sorted slice.
#define GATHER4(p_, sorted_, st_, nn_, fb_, part_)                     \
    {                                                                  \
        int i = (part_);                                               \
        for (; i + 28 < (nn_); i += 32) {                              \
            int s0 = (sorted_)[(st_) + i + 0],  s1 = (sorted_)[(st_) + i + 4];  \
            int s2 = (sorted_)[(st_) + i + 8],  s3 = (sorted_)[(st_) + i + 12]; \
            int s4 = (sorted_)[(st_) + i + 16], s5 = (sorted_)[(st_) + i + 20]; \
            int s6 = (sorted_)[(st_) + i + 24], s7 = (sorted_)[(st_) + i + 28]; \
            float4 r0 = *(const float4*)((p_) + (size_t)s0 * HID + (fb_)); \
            float4 r1 = *(const float4*)((p_) + (size_t)s1 * HID + (fb_)); \
            float4 r2 = *(const float4*)((p_) + (size_t)s2 * HID + (fb_)); \
            float4 r3 = *(const float4*)((p_) + (size_t)s3 * HID + (fb_)); \
            float4 r4 = *(const float4*)((p_) + (size_t)s4 * HID + (fb_)); \
            float4 r5 = *(const float4*)((p_) + (size_t)s5 * HID + (fb_)); \
            float4 r6 = *(const float4*)((p_) + (size_t)s6 * HID + (fb_)); \
            float4 r7 = *(const float4*)((p_) + (size_t)s7 * HID + (fb_)); \
            ACC8(r0); ACC8(r1); ACC8(r2); ACC8(r3);                    \
            ACC8(r4); ACC8(r5); ACC8(r6); ACC8(r7);                    \
        }                                                              \
        for (; i < (nn_); i += 4) {                                    \
            int s = (sorted_)[(st_) + i];                              \
            float4 raw = *(const float4*)((p_) + (size_t)s * HID + (fb_)); \
            ACC8(raw);                                                 \
        }                                                              \
    }

// Combine the 4 part-partials (threads sub, sub^2, sub^4 hold same half).
#define PART_COMBINE()                                                 \
    {                                                                  \
        a0 += __shfl_xor(a0, 2); a1 += __shfl_xor(a1, 2);              \
        a2 += __shfl_xor(a2, 2); a3 += __shfl_xor(a3, 2);              \
        a4 += __shfl_xor(a4, 2); a5 += __shfl_xor(a5, 2);              \
        a6 += __shfl_xor(a6, 2); a7 += __shfl_xor(a7, 2);              \
        a0 += __shfl_xor(a0, 4); a1 += __shfl_xor(a1, 4);              \
        a2 += __shfl_xor(a2, 4); a3 += __shfl_xor(a3, 4);              \
        a4 += __shfl_xor(a4, 4); a5 += __shfl_xor(a5, 4);              \
        a6 += __shfl_xor(a6, 4); a7 += __shfl_xor(a7, 4);              \
    }

// Shared epilogue: mean + bias + root + relu -> h
__device__ __forceinline__ void agg_epilogue(
    float a0, float a1, float a2, float a3,
    float a4, float a5, float a6, float a7,
    int n_cnt, int fb, int node,
    const __half* __restrict__ q, const float* __restrict__ b,
    __half* __restrict__ h)
{
    float inv = 1.f / fmaxf((float)n_cnt, 1.f);
    float4 qraw = *(const float4*)(q + (size_t)node * HID + fb);
    float2 q0 = __half22float2(*(const __half2*)&qraw.x);
    float2 q1 = __half22float2(*(const __half2*)&qraw.y);
    float2 q2 = __half22float2(*(const __half2*)&qraw.z);
    float2 q3 = __half22float2(*(const __half2*)&qraw.w);

    __half2 r0 = __floats2half2_rn(fmaxf(a0*inv + b[fb+0] + q0.x, 0.f),
                                   fmaxf(a1*inv + b[fb+1] + q0.y, 0.f));
    __half2 r1 = __floats2half2_rn(fmaxf(a2*inv + b[fb+2] + q1.x, 0.f),
                                   fmaxf(a3*inv + b[fb+3] + q1.y, 0.f));
    __half2 r2 = __floats2half2_rn(fmaxf(a4*inv + b[fb+4] + q2.x, 0.f),
                                   fmaxf(a5*inv + b[fb+5] + q2.y, 0.f));
    __half2 r3 = __floats2half2_rn(fmaxf(a6*inv + b[fb+6] + q3.x, 0.f),
                                   fmaxf(a7*inv + b[fb+7] + q3.y, 0.f));
    float4 res;
    *(__half2*)&res.x = r0; *(__half2*)&res.y = r1;
    *(__half2*)&res.z = r2; *(__half2*)&res.w = r3;
    *(float4*)(h + (size_t)node * HID + fb) = res;
}

// ---------------------------------------------------------------------------
// R7: bucket sort only — in-LDS counting sort, persist CSR (sorted src +
// per-node off/cnt). Gathers moved to dedicated high-occupancy kernels.
__global__ __launch_bounds__(256) void bucket_sort_kernel(
    const int* __restrict__ cursor, const int* __restrict__ recs,
    const int* __restrict__ ovf_cnt, const int2* __restrict__ ovf,
    int N, int K,
    int* __restrict__ g_sorted, int* __restrict__ g_cnt,
    int* __restrict__ g_off)
{
    __shared__ int sorted[SMAX];
    __shared__ int cnt[NPB];
    __shared__ int off[NPB];
    __shared__ int cur[NPB];
    __shared__ int scan[NPB];
    __shared__ int s_ovf;

    int bkt = blockIdx.x;
    int tid = threadIdx.x;

    if (tid < NPB) cnt[tid] = 0;
    if (tid == 0) { int v = *ovf_cnt; s_ovf = v < OVF_CAP ? v : OVF_CAP; }
    __syncthreads();

    for (int xcd = 0; xcd < NXCD; ++xcd) {
        int cell = xcd * K + bkt;
        int len = cursor[cell]; if (len > CAP) len = CAP;
        const int* cr = recs + (size_t)cell * CAP;
        for (int r = tid; r < len; r += 256)
            atomicAdd(&cnt[((unsigned)cr[r]) >> 17], 1);
    }
    if (s_ovf > 0) {
        for (int r = tid; r < s_ovf; r += 256) {
            int2 od = ovf[r];
            if ((od.x >> 7) == bkt) atomicAdd(&cnt[od.x & 127], 1);
        }
    }
    __syncthreads();

    if (tid < NPB) scan[tid] = cnt[tid];
    __syncthreads();
    for (int o = 1; o < NPB; o <<= 1) {
        int v = 0;
        if (tid < NPB && tid >= o) v = scan[tid - o];
        __syncthreads();
        if (tid < NPB) scan[tid] += v;
        __syncthreads();
    }
    if (tid < NPB) { int e = scan[tid] - cnt[tid]; off[tid] = e; cur[tid] = e; }
    __syncthreads();

    for (int xcd = 0; xcd < NXCD; ++xcd) {
        int cell = xcd * K + bkt;
        int len = cursor[cell]; if (len > CAP) len = CAP;
        const int* cr = recs + (size_t)cell * CAP;
        for (int r = tid; r < len; r += 256) {
            int rec = cr[r];
            int slot = atomicAdd(&cur[((unsigned)rec) >> 17], 1);
            if (slot < SMAX) sorted[slot] = rec & 0x1FFFF;
        }
    }
    if (s_ovf > 0) {
        for (int r = tid; r < s_ovf; r += 256) {
            int2 od = ovf[r];
            if ((od.x >> 7) == bkt) {
                int slot = atomicAdd(&cur[od.x & 127], 1);
                if (slot < SMAX) sorted[slot] = od.y;
            }
        }
    }
    __syncthreads();

    int total = off[NPB - 1] + cnt[NPB - 1];
    if (total > SMAX) total = SMAX;
    int* gs = g_sorted + (size_t)bkt * SMAX;
    for (int i = tid; i < total; i += 256) gs[i] = sorted[i];
    if (tid < NPB) {
        g_cnt[bkt * NPB + tid] = cnt[tid];
        g_off[bkt * NPB + tid] = off[tid];
    }
}

// ---------------------------------------------------------------------------
// R7: gather #1 fused with gemm2. 4 blocks/bucket, 32 nodes/block,
// 8 threads/node (half x part0..3). Loads only the block's contiguous CSR
// slice into LDS. Epilogue: h1 (f32, registers) -> LDS -> W2 matvec ->
// p2/q2 (fresh buffers; other blocks still gather p1 rows).
__global__ __launch_bounds__(256) void gather1_fused_kernel(
    const int* __restrict__ g_sorted, const int* __restrict__ g_cnt,
    const int* __restrict__ g_off,
    const __half* __restrict__ p, const __half* __restrict__ q,
    const float* __restrict__ b1,
    const float* __restrict__ w2l, const float* __restrict__ w2r,
    __half* __restrict__ p2, __half* __restrict__ q2, int N, int K)
{
    __shared__ int sorted[SMAX];
    __shared__ int cnt[GNODES];
    __shared__ int off[GNODES];

    int bkt = blockIdx.x >> 2;
    int nb  = blockIdx.x & 3;
    int tid = threadIdx.x;
    int nbase = bkt * NPB + nb * GNODES;

    if (tid < GNODES) {
        cnt[tid] = g_cnt[nbase + tid];
        off[tid] = g_off[nbase + tid];
    }
    __syncthreads();

    int off0 = off[0];            if (off0 > SMAX) off0 = SMAX;
    int end  = off[GNODES - 1] + cnt[GNODES - 1];
    if (end > SMAX) end = SMAX;
    int slen = end - off0; if (slen < 0) slen = 0;
    const int* gs = g_sorted + (size_t)bkt * SMAX + off0;
    for (int i = tid; i < slen; i += 256) sorted[i] = gs[i];
    __syncthreads();

    int dl   = tid >> 3;          // node within the 32
    int sub  = tid & 7;
    int half = sub & 1;
    int part = sub >> 1;          // 0..3
    int node = (bkt << 7) + nb * GNODES + dl;
    bool act = node < N;

    int st = 0, nn = 0, fb = half * 8;
    if (act) {
        st = off[dl]; if (st > SMAX) st = SMAX;
        nn = cnt[dl]; if (st + nn > SMAX) nn = SMAX - st;
        st -= off0;               // LDS-relative
    }

    float a0 = 0.f, a1 = 0.f, a2 = 0.f, a3 = 0.f,
          a4 = 0.f, a5 = 0.f, a6 = 0.f, a7 = 0.f;
    GATHER4(p, sorted, st, nn, fb, part);
    PART_COMBINE();

    float h1v[8];
    if (act && part == 0) {
        float inv = 1.f / fmaxf((float)cnt[dl], 1.f);
        float4 qraw = *(const float4*)(q + (size_t)node * HID + fb);
        float2 q0 = __half22float2(*(const __half2*)&qraw.x);
        float2 q1 = __half22float2(*(const __half2*)&qraw.y);
        float2 q2v = __half22float2(*(const __half2*)&qraw.z);
        float2 q3 = __half22float2(*(const __half2*)&qraw.w);
        h1v[0] = fmaxf(a0*inv + b1[fb+0] + q0.x, 0.f);
        h1v[1] = fmaxf(a1*inv + b1[fb+1] + q0.y, 0.f);
        h1v[2] = fmaxf(a2*inv + b1[fb+2] + q1.x, 0.f);
        h1v[3] = fmaxf(a3*inv + b1[fb+3] + q1.y, 0.f);
        h1v[4] = fmaxf(a4*inv + b1[fb+4] + q2v.x, 0.f);
        h1v[5] = fmaxf(a5*inv + b1[fb+5] + q2v.y, 0.f);
        h1v[6] = fmaxf(a6*inv + b1[fb+6] + q3.x, 0.f);
        h1v[7] = fmaxf(a7*inv + b1[fb+7] + q3.y, 0.f);
    }
    __syncthreads();              // all sorted[] reads complete

    // Stage h1 rows in LDS (alias sorted; stride 17 -> conflict-free)
    float* hl = (float*)sorted;   // 32*17 = 544 floats << SMAX
    if (act && part == 0) {
        #pragma unroll
        for (int j = 0; j < 8; ++j) hl[dl * 17 + fb + j] = h1v[j];
    }
    __syncthreads();

    if (act && part == 0) {
        float hv[16];
        #pragma unroll
        for (int k = 0; k < HID; ++k) hv[k] = hl[dl * 17 + k];

        float accl[8], accr[8];
        #pragma unroll
        for (int f = 0; f < 8; ++f) { accl[f] = 0.f; accr[f] = 0.f; }
        #pragma unroll
        for (int k = 0; k < HID; ++k) {
            float hs = hv[k];
            #pragma unroll
            for (int f = 0; f < 8; ++f) {
                accl[f] = fmaf(hs, w2l[k * HID + fb + f], accl[f]);
                accr[f] = fmaf(hs, w2r[k * HID + fb + f], accr[f]);
            }
        }

        __half2 po[4], qo[4];
        #pragma unroll
        for (int f = 0; f < 4; ++f) {
            po[f] = __floats2half2_rn(accl[2*f], accl[2*f+1]);
            qo[f] = __floats2half2_rn(accr[2*f], accr[2*f+1]);
        }
        *(float4*)(p2 + (size_t)node * HID + fb) = *(float4*)&po[0];
        *(float4*)(q2 + (size_t)node * HID + fb) = *(float4*)&qo[0];
    }
}

// ---------------------------------------------------------------------------
// R7: gather #2 — same 4-blocks/bucket structure, standard epilogue.
// h may alias q (own-node row read-then-written by the same threads).
__global__ __launch_bounds__(256) void gather2_kernel(
    const int* __restrict__ g_sorted, const int* __restrict__ g_cnt,
    const int* __restrict__ g_off,
    const __half* __restrict__ p, const __half* __restrict__ q,
    const float* __restrict__ b, __half* __restrict__ h, int N, int K)
{
    __shared__ int sorted[SMAX];
    __shared__ int cnt[GNODES];
    __shared__ int off[GNODES];

    int bkt = blockIdx.x >> 2;
    int nb  = blockIdx.x & 3;
    int tid = threadIdx.x;
    int nbase = bkt * NPB + nb * GNODES;

    if (tid < GNODES) {
        cnt[tid] = g_cnt[nbase + tid];
        off[tid] = g_off[nbase + tid];
    }
    __syncthreads();

    int off0 = off[0];            if (off0 > SMAX) off0 = SMAX;
    int end  = off[GNODES - 1] + cnt[GNODES - 1];
    if (end > SMAX) end = SMAX;
    int slen = end - off0; if (slen < 0) slen = 0;
    const int* gs = g_sorted + (size_t)bkt * SMAX + off0;
    for (int i = tid; i < slen; i += 256) sorted[i] = gs[i];
    __syncthreads();

    int dl   = tid >> 3;
    int sub  = tid & 7;
    int half = sub & 1;
    int part = sub >> 1;
    int node = (bkt << 7) + nb * GNODES + dl;
    bool act = node < N;

    int st = 0, nn = 0, fb = half * 8;
    if (act) {
        st = off[dl]; if (st > SMAX) st = SMAX;
        nn = cnt[dl]; if (st + nn > SMAX) nn = SMAX - st;
        st -= off0;
    }

    float a0 = 0.f, a1 = 0.f, a2 = 0.f, a3 = 0.f,
          a4 = 0.f, a5 = 0.f, a6 = 0.f, a7 = 0.f;
    GATHER4(p, sorted, st, nn, fb, part);
    PART_COMBINE();

    if (act && part == 0)
        agg_epilogue(a0, a1, a2, a3, a4, a5, a6, a7, cnt[dl], fb, node, q, b, h);
}

// ---------------------------------------------------------------------------
// MFMA edge MLP, transposed form. R5: fc2 reduction via a SECOND MFMA
// (16x16x16) instead of the shfl_xor chain. The first MFMA's C layout
// (lane(q,n) holds Z[k=q*4+r][edge n]) is exactly the K=16 B-fragment
// layout; A = W2^T zero-padded to 16 rows. Lanes q==0 get both class
// logits in acc2[0..1] and store coalesced float2.
__global__ __launch_bounds__(256) void edge_mlp_mfma_kernel(
    const int* __restrict__ src, const int* __restrict__ dst,
    const __half* __restrict__ h,
    const float* __restrict__ fc1w, const float* __restrict__ fc1b,
    const float* __restrict__ fc2w, const float* __restrict__ fc2b,
    float* __restrict__ out, int E, int ntiles)
{
    int lane   = threadIdx.x & 63;
    int wave   = (blockIdx.x * blockDim.x + threadIdx.x) >> 6;
    int nwaves = (gridDim.x * blockDim.x) >> 6;

    int n = lane & 15;      // edge within tile (B col, C col); also A row
    int q = lane >> 4;      // quad

    // fc1 A-fragment = W1^T: A[m=lane&15][k=q*8+j] = fc1w[(q*8+j)*16 + m]
    half8 wfrag;
    #pragma unroll
    for (int j = 0; j < 8; ++j)
        wfrag[j] = (_Float16)fc1w[(q * 8 + j) * 16 + n];

    // fc2 A-fragment (K=16): A[m=lane&15][k=q*4+j] = fc2w[(q*4+j)*2 + m], m<2
    half4 w2frag;
    #pragma unroll
    for (int j = 0; j < 4; ++j)
        w2frag[j] = (n < 2) ? (_Float16)fc2w[(q * 4 + j) * 2 + n]
                            : (_Float16)0.f;

    // fc1 bias for this lane's 4 z-rows (k = q*4+r)
    float bias1[4];
    #pragma unroll
    for (int r = 0; r < 4; ++r) bias1[r] = fc1b[q * 4 + r];
    float bb0 = fc2b[0], bb1 = fc2b[1];

    const int* tp = (q < 2) ? src : dst;
    int hoff = (q & 1) * 8;

    for (int t = wave; t < ntiles; t += nwaves) {
        int e   = t * 16 + n;
        int e_c = e < E ? e : E - 1;
        int idx = tp[e_c];
        half8 xf = *(const half8*)(h + (size_t)idx * HID + hoff);

        floatx4 acc = {0.f, 0.f, 0.f, 0.f};
        acc = __builtin_amdgcn_mfma_f32_16x16x32_f16(wfrag, xf, acc, 0, 0, 0);

        // z = relu(acc + b1) -> fp16 B-fragment for the fc2 MFMA
        half4 z;
        #pragma unroll
        for (int r = 0; r < 4; ++r)
            z[r] = (_Float16)fmaxf(acc[r] + bias1[r], 0.f);

        floatx4 acc2 = {0.f, 0.f, 0.f, 0.f};
        acc2 = __builtin_amdgcn_mfma_f32_16x16x16f16(w2frag, z, acc2, 0, 0, 0);

        if (q == 0) {
            int eo = t * 16 + n;
            if (eo < E) {
                float a  = acc2[0] + bb0;
                float c  = acc2[1] + bb1;
                float mx = fmaxf(a, c);
                float lse = mx + __logf(__expf(a - mx) + __expf(c - mx));
                ((float2*)out)[eo] = make_float2(a - lse, c - lse);
            }
        }
    }
}

// ---------------------------------------------------------------------------
extern "C" void kernel_launch(void* const* d_in, const int* in_sizes, int n_in,
                              void* d_out, int out_size, void* d_ws, size_t ws_size,
                              hipStream_t stream)
{
    const float* x    = (const float*)d_in[0];
    const int*   ei   = (const int*)  d_in[1];
    const float* w1l  = (const float*)d_in[2];
    const float* b1l  = (const float*)d_in[3];
    const float* w1r  = (const float*)d_in[4];
    const float* w2l  = (const float*)d_in[5];
    const float* b2l  = (const float*)d_in[6];
    const float* w2r  = (const float*)d_in[7];
    const float* fc1w = (const float*)d_in[8];
    const float* fc1b = (const float*)d_in[9];
    const float* fc2w = (const float*)d_in[10];
    const float* fc2b = (const float*)d_in[11];
    float* out = (float*)d_out;

    int N = in_sizes[0] / NF;
    int E = in_sizes[1] / 2;
    const int* src = ei;
    const int* dst = ei + E;

    int K = (N + NPB - 1) / NPB;   // 782 buckets (<= KMAX)

    // ws: A16|B16|C16|D16 | recs | cursor | ovf_cnt | ovf | g_sorted|g_cnt|g_off
    __half* A16      = (__half*)d_ws;            // p1
    __half* B16      = A16 + (size_t)N * HID;    // q1
    __half* C16      = B16 + (size_t)N * HID;    // p2
    __half* D16      = C16 + (size_t)N * HID;    // q2 -> h2 (in-place)
    int*    recs     = (int*)(D16 + (size_t)N * HID);
    int*    cursor   = recs + (size_t)NXCD * K * CAP;
    int*    ovfcnt   = cursor + (size_t)NXCD * K;
    int2*   ovf      = (int2*)(ovfcnt + 2);
    int*    g_sorted = (int*)(ovf + OVF_CAP);
    int*    g_cnt    = g_sorted + (size_t)K * SMAX;
    int*    g_off    = g_cnt + (size_t)K * NPB;

    int ncur = NXCD * K + 1;

    zero_kernel<<<(ncur + 255) / 256, 256, 0, stream>>>(cursor, ncur);
    scatter_bin_kernel<<<(E + CH - 1) / CH, 256, 0, stream>>>(src, dst, cursor, recs,
                                                              ovfcnt, ovf, E, K);

    int ntiles_n = (N + 15) / 16;            // 6250
    int gemm_blocks = (ntiles_n + 7) / 8;    // 2 tiles per wave, balanced

    gemm1_kernel<<<gemm_blocks, 256, 0, stream>>>(x, w1l, w1r, A16, B16, N, ntiles_n);

    // Build CSR once (sort only)
    bucket_sort_kernel<<<K, 256, 0, stream>>>(cursor, recs, ovfcnt, ovf, N, K,
                                              g_sorted, g_cnt, g_off);

    // Layer-1 gather fused with gemm2: p2->C16, q2->D16
    gather1_fused_kernel<<<K * GBLK, 256, 0, stream>>>(g_sorted, g_cnt, g_off,
                                                       A16, B16, b1l, w2l, w2r,
                                                       C16, D16, N, K);

    // Layer-2 gather: h2 = relu(mean(p2)+b2+q2), in-place over D16
    gather2_kernel<<<K * GBLK, 256, 0, stream>>>(g_sorted, g_cnt, g_off,
                                                 C16, D16, b2l, D16, N, K);

    int ntiles = (E + 15) / 16;
    edge_mlp_mfma_kernel<<<2048, 256, 0, stream>>>(src, dst, D16, fc1w, fc1b,
                                                   fc2w, fc2b, out, E, ntiles);
}

// Round 8
// 278.723 us; speedup vs baseline: 1.0379x; 1.0379x over previous
//
#include <hip/hip_runtime.h>
#include <hip/hip_fp16.h>
#include <math.h>

#define NF   128
#define HID  16
#define NPB  64           // nodes per bucket (dst >> 6)  [R8: 128->64]
#define NPB_SH 6
#define CAP  384          // records per (xcd, bucket) cell; mean 256
#define NXCD 8
#define SMAX (NXCD * CAP) // max records per bucket in LDS sort (3072)
#define OVF_CAP 262144    // statistically-unreachable overflow list
#define KMAX 2048         // max buckets (N <= 131072)
#define CH   2048         // edges per block in scatter_bin (8/thread, reg-cached)

typedef _Float16 half8 __attribute__((ext_vector_type(8)));
typedef _Float16 half4 __attribute__((ext_vector_type(4)));
typedef float    floatx4 __attribute__((ext_vector_type(4)));

// ---------------------------------------------------------------------------
__global__ void zero_kernel(int* __restrict__ ptr, int n) {
    int i = blockIdx.x * blockDim.x + threadIdx.x;
    if (i < n) ptr[i] = 0;
}

// ---------------------------------------------------------------------------
// Block-chunked two-pass binning: LDS histogram -> one XCD-local L2 atomic
// per touched bucket -> private contiguous range fill.
// Record = (dst & 63) << 17 | src   (src < 2^17).
__global__ __launch_bounds__(256) void scatter_bin_kernel(
    const int* __restrict__ src, const int* __restrict__ dst,
    int* __restrict__ cursor, int* __restrict__ recs,
    int* __restrict__ ovf_cnt, int2* __restrict__ ovf, int E, int K)
{
    __shared__ int cnt[KMAX];
    __shared__ int resbase[KMAX];
    __shared__ int cur[KMAX];

    int tid  = threadIdx.x;
    int base = blockIdx.x * CH;

    for (int b = tid; b < K; b += 256) cnt[b] = 0;
    __syncthreads();

    int ebase = base + tid * 8;
    int4 da = {0,0,0,0}, db = {0,0,0,0}, sa = {0,0,0,0}, sb = {0,0,0,0};
    if (ebase + 8 <= E) {
        da = ((const int4*)(dst + ebase))[0];
        db = ((const int4*)(dst + ebase))[1];
        sa = ((const int4*)(src + ebase))[0];
        sb = ((const int4*)(src + ebase))[1];
    } else if (ebase < E) {
        int m = E - ebase;
        if (m > 0) { da.x = dst[ebase+0]; sa.x = src[ebase+0]; }
        if (m > 1) { da.y = dst[ebase+1]; sa.y = src[ebase+1]; }
        if (m > 2) { da.z = dst[ebase+2]; sa.z = src[ebase+2]; }
        if (m > 3) { da.w = dst[ebase+3]; sa.w = src[ebase+3]; }
        if (m > 4) { db.x = dst[ebase+4]; sb.x = src[ebase+4]; }
        if (m > 5) { db.y = dst[ebase+5]; sb.y = src[ebase+5]; }
        if (m > 6) { db.z = dst[ebase+6]; sb.z = src[ebase+6]; }
    }
    int ne = E - ebase; ne = ne < 0 ? 0 : (ne > 8 ? 8 : ne);
    int d[8] = {da.x, da.y, da.z, da.w, db.x, db.y, db.z, db.w};
    int s[8] = {sa.x, sa.y, sa.z, sa.w, sb.x, sb.y, sb.z, sb.w};

    #pragma unroll
    for (int i = 0; i < 8; ++i)
        if (i < ne) atomicAdd(&cnt[((unsigned)d[i]) >> NPB_SH], 1);
    __syncthreads();

    int xcd;
    asm volatile("s_getreg_b32 %0, hwreg(HW_REG_XCC_ID)" : "=s"(xcd));
    xcd &= 7;

    for (int b = tid; b < K; b += 256) {
        int c = cnt[b];
        cur[b] = 0;
        if (c > 0)
            resbase[b] = __hip_atomic_fetch_add(&cursor[xcd * K + b], c,
                                                __ATOMIC_RELAXED,
                                                __HIP_MEMORY_SCOPE_WORKGROUP);
    }
    __syncthreads();

    #pragma unroll
    for (int i = 0; i < 8; ++i) {
        if (i >= ne) break;
        int b = ((unsigned)d[i]) >> NPB_SH;
        int idx  = atomicAdd(&cur[b], 1);          // LDS
        int slot = resbase[b] + idx;
        if (slot < CAP) {
            recs[((size_t)(xcd * K + b)) * CAP + slot] =
                ((d[i] & (NPB - 1)) << 17) | s[i];
        } else {
            int op = atomicAdd(ovf_cnt, 1);        // device scope; ~never
            if (op < OVF_CAP) ovf[op] = make_int2(d[i], s[i]);
        }
    }
}

// ---------------------------------------------------------------------------
// R3: MFMA gemm1. One wave = 16-node tile. A-frag = W^T in registers as
// fp16 hi/lo split pairs. B-frag = 32B of the lane's x row per K-step.
// C = P^T: lane(quad,n) holds features quad*4..+3 of node n -> 8B stores.
__global__ __launch_bounds__(256, 4) void gemm1_kernel(
    const float* __restrict__ x, const float* __restrict__ wl,
    const float* __restrict__ wr, __half* __restrict__ p,
    __half* __restrict__ q, int N, int ntiles)
{
    int lane   = threadIdx.x & 63;
    int wave   = (blockIdx.x * blockDim.x + threadIdx.x) >> 6;
    int nwaves = (gridDim.x * blockDim.x) >> 6;

    int m  = lane & 15;   // A row (feature) / B col (node) / C col (node)
    int qd = lane >> 4;   // quad

    half8 wlh[4], wll[4], wrh[4], wrl[4];
    #pragma unroll
    for (int kk = 0; kk < 4; ++kk) {
        #pragma unroll
        for (int j = 0; j < 8; ++j) {
            int k = kk * 32 + qd * 8 + j;
            float a = wl[k * HID + m];
            _Float16 ah = (_Float16)a;
            wlh[kk][j] = ah;
            wll[kk][j] = (_Float16)(a - (float)ah);
            float b = wr[k * HID + m];
            _Float16 bh = (_Float16)b;
            wrh[kk][j] = bh;
            wrl[kk][j] = (_Float16)(b - (float)bh);
        }
    }

    for (int t = wave; t < ntiles; t += nwaves) {
        int node = t * 16 + m;
        int nc   = node < N ? node : N - 1;
        const float4* xr = (const float4*)(x + (size_t)nc * NF);

        floatx4 accl = {0.f, 0.f, 0.f, 0.f};
        floatx4 accr = {0.f, 0.f, 0.f, 0.f};

        #pragma unroll
        for (int kk = 0; kk < 4; ++kk) {
            float4 v0 = xr[kk * 8 + qd * 2 + 0];
            float4 v1 = xr[kk * 8 + qd * 2 + 1];
            float xs[8] = {v0.x, v0.y, v0.z, v0.w, v1.x, v1.y, v1.z, v1.w};
            half8 xh, xlo;
            #pragma unroll
            for (int j = 0; j < 8; ++j) {
                _Float16 hh = (_Float16)xs[j];
                xh[j]  = hh;
                xlo[j] = (_Float16)(xs[j] - (float)hh);
            }
            accl = __builtin_amdgcn_mfma_f32_16x16x32_f16(wlh[kk], xh,  accl, 0, 0, 0);
            accr = __builtin_amdgcn_mfma_f32_16x16x32_f16(wrh[kk], xh,  accr, 0, 0, 0);
            accl = __builtin_amdgcn_mfma_f32_16x16x32_f16(wll[kk], xh,  accl, 0, 0, 0);
            accr = __builtin_amdgcn_mfma_f32_16x16x32_f16(wrl[kk], xh,  accr, 0, 0, 0);
            accl = __builtin_amdgcn_mfma_f32_16x16x32_f16(wlh[kk], xlo, accl, 0, 0, 0);
            accr = __builtin_amdgcn_mfma_f32_16x16x32_f16(wrh[kk], xlo, accr, 0, 0, 0);
        }

        if (node < N) {
            float2 pv, qv;
            *(__half2*)&pv.x = __floats2half2_rn(accl[0], accl[1]);
            *(__half2*)&pv.y = __floats2half2_rn(accl[2], accl[3]);
            *(__half2*)&qv.x = __floats2half2_rn(accr[0], accr[1]);
            *(__half2*)&qv.y = __floats2half2_rn(accr[2], accr[3]);
            *(float2*)(p + (size_t)node * HID + qd * 4) = pv;
            *(float2*)(q + (size_t)node * HID + qd * 4) = qv;
        }
    }
}

// ---------------------------------------------------------------------------
// Accumulate helper: 8 features from a 16B half-row.
#define ACC8(raw)                                                      \
    {                                                                  \
        float2 v0 = __half22float2(*(const __half2*)&(raw).x);         \
        float2 v1 = __half22float2(*(const __half2*)&(raw).y);         \
        float2 v2 = __half22float2(*(const __half2*)&(raw).z);         \
        float2 v3 = __half22float2(*(const __half2*)&(raw).w);         \
        a0 += v0.x; a1 += v0.y; a2 += v1.x; a3 += v1.y;                \
        a4 += v2.x; a5 += v2.y; a6 += v3.x; a7 += v3.y;                \
    }

// Stride-2 (parity-split) 8-deep unrolled gather-accumulate.
#define GATHER2(p_, sorted_, st_, nn_, fb_, part_)                     \
    {                                                                  \
        int i = (part_);                                               \
        for (; i + 14 < (nn_); i += 16) {                              \
            int s0 = (sorted_)[(st_) + i + 0],  s1 = (sorted_)[(st_) + i + 2];  \
            int s2 = (sorted_)[(st_) + i + 4],  s3 = (sorted_)[(st_) + i + 6];  \
            int s4 = (sorted_)[(st_) + i + 8],  s5 = (sorted_)[(st_) + i + 10]; \
            int s6 = (sorted_)[(st_) + i + 12], s7 = (sorted_)[(st_) + i + 14]; \
            float4 r0 = *(const float4*)((p_) + (size_t)s0 * HID + (fb_)); \
            float4 r1 = *(const float4*)((p_) + (size_t)s1 * HID + (fb_)); \
            float4 r2 = *(const float4*)((p_) + (size_t)s2 * HID + (fb_)); \
            float4 r3 = *(const float4*)((p_) + (size_t)s3 * HID + (fb_)); \
            float4 r4 = *(const float4*)((p_) + (size_t)s4 * HID + (fb_)); \
            float4 r5 = *(const float4*)((p_) + (size_t)s5 * HID + (fb_)); \
            float4 r6 = *(const float4*)((p_) + (size_t)s6 * HID + (fb_)); \
            float4 r7 = *(const float4*)((p_) + (size_t)s7 * HID + (fb_)); \
            ACC8(r0); ACC8(r1); ACC8(r2); ACC8(r3);                    \
            ACC8(r4); ACC8(r5); ACC8(r6); ACC8(r7);                    \
        }                                                              \
        for (; i < (nn_); i += 2) {                                    \
            int s = (sorted_)[(st_) + i];                              \
            float4 raw = *(const float4*)((p_) + (size_t)s * HID + (fb_)); \
            ACC8(raw);                                                 \
        }                                                              \
    }

// Combine parity partials: threads tid and tid^2 hold the two halves.
#define PARITY_COMBINE()                                               \
    {                                                                  \
        a0 += __shfl_xor(a0, 2); a1 += __shfl_xor(a1, 2);              \
        a2 += __shfl_xor(a2, 2); a3 += __shfl_xor(a3, 2);              \
        a4 += __shfl_xor(a4, 2); a5 += __shfl_xor(a5, 2);              \
        a6 += __shfl_xor(a6, 2); a7 += __shfl_xor(a7, 2);              \
    }

// Shared epilogue: mean + bias + root + relu -> h
__device__ __forceinline__ void agg_epilogue(
    float a0, float a1, float a2, float a3,
    float a4, float a5, float a6, float a7,
    int n_cnt, int fb, int node,
    const __half* __restrict__ q, const float* __restrict__ b,
    __half* __restrict__ h)
{
    float inv = 1.f / fmaxf((float)n_cnt, 1.f);
    float4 qraw = *(const float4*)(q + (size_t)node * HID + fb);
    float2 q0 = __half22float2(*(const __half2*)&qraw.x);
    float2 q1 = __half22float2(*(const __half2*)&qraw.y);
    float2 q2 = __half22float2(*(const __half2*)&qraw.z);
    float2 q3 = __half22float2(*(const __half2*)&qraw.w);

    __half2 r0 = __floats2half2_rn(fmaxf(a0*inv + b[fb+0] + q0.x, 0.f),
                                   fmaxf(a1*inv + b[fb+1] + q0.y, 0.f));
    __half2 r1 = __floats2half2_rn(fmaxf(a2*inv + b[fb+2] + q1.x, 0.f),
                                   fmaxf(a3*inv + b[fb+3] + q1.y, 0.f));
    __half2 r2 = __floats2half2_rn(fmaxf(a4*inv + b[fb+4] + q2.x, 0.f),
                                   fmaxf(a5*inv + b[fb+5] + q2.y, 0.f));
    __half2 r3 = __floats2half2_rn(fmaxf(a6*inv + b[fb+6] + q3.x, 0.f),
                                   fmaxf(a7*inv + b[fb+7] + q3.y, 0.f));
    float4 res;
    *(__half2*)&res.x = r0; *(__half2*)&res.y = r1;
    *(__half2*)&res.z = r2; *(__half2*)&res.w = r3;
    *(float4*)(h + (size_t)node * HID + fb) = res;
}

// ---------------------------------------------------------------------------
// R8: agg#1 fused with gemm2 (R5 structure, NPB=64). In-LDS counting sort +
// CSR persist + gather (4 threads/node: half x parity), then h1 stays in
// registers/LDS and the 16x16 W2 matvec writes p2->C16, q2->D16.
__global__ __launch_bounds__(256) void bucket_agg1_fused_kernel(
    const int* __restrict__ cursor, const int* __restrict__ recs,
    const int* __restrict__ ovf_cnt, const int2* __restrict__ ovf,
    const __half* __restrict__ p, const __half* __restrict__ q,
    const float* __restrict__ b1,
    const float* __restrict__ w2l, const float* __restrict__ w2r,
    __half* __restrict__ p2, __half* __restrict__ q2, int N, int K,
    int* __restrict__ g_sorted, int* __restrict__ g_cnt,
    int* __restrict__ g_off)
{
    __shared__ int sorted[SMAX];
    __shared__ int cnt[NPB];
    __shared__ int off[NPB];
    __shared__ int cur[NPB];
    __shared__ int scan[NPB];
    __shared__ int s_ovf;

    int bkt = blockIdx.x;
    int tid = threadIdx.x;

    if (tid < NPB) cnt[tid] = 0;
    if (tid == 0) { int v = *ovf_cnt; s_ovf = v < OVF_CAP ? v : OVF_CAP; }
    __syncthreads();

    for (int xcd = 0; xcd < NXCD; ++xcd) {
        int cell = xcd * K + bkt;
        int len = cursor[cell]; if (len > CAP) len = CAP;
        const int* cr = recs + (size_t)cell * CAP;
        for (int r = tid; r < len; r += 256)
            atomicAdd(&cnt[((unsigned)cr[r]) >> 17], 1);
    }
    if (s_ovf > 0) {
        for (int r = tid; r < s_ovf; r += 256) {
            int2 od = ovf[r];
            if ((od.x >> NPB_SH) == bkt) atomicAdd(&cnt[od.x & (NPB - 1)], 1);
        }
    }
    __syncthreads();

    if (tid < NPB) scan[tid] = cnt[tid];
    __syncthreads();
    for (int o = 1; o < NPB; o <<= 1) {
        int v = 0;
        if (tid < NPB && tid >= o) v = scan[tid - o];
        __syncthreads();
        if (tid < NPB) scan[tid] += v;
        __syncthreads();
    }
    if (tid < NPB) { int e = scan[tid] - cnt[tid]; off[tid] = e; cur[tid] = e; }
    __syncthreads();

    for (int xcd = 0; xcd < NXCD; ++xcd) {
        int cell = xcd * K + bkt;
        int len = cursor[cell]; if (len > CAP) len = CAP;
        const int* cr = recs + (size_t)cell * CAP;
        for (int r = tid; r < len; r += 256) {
            int rec = cr[r];
            int slot = atomicAdd(&cur[((unsigned)rec) >> 17], 1);
            if (slot < SMAX) sorted[slot] = rec & 0x1FFFF;
        }
    }
    if (s_ovf > 0) {
        for (int r = tid; r < s_ovf; r += 256) {
            int2 od = ovf[r];
            if ((od.x >> NPB_SH) == bkt) {
                int slot = atomicAdd(&cur[od.x & (NPB - 1)], 1);
                if (slot < SMAX) sorted[slot] = od.y;
            }
        }
    }
    __syncthreads();

    // Persist CSR for the second aggregation pass.
    int total = off[NPB - 1] + cnt[NPB - 1];
    if (total > SMAX) total = SMAX;
    int* gs = g_sorted + (size_t)bkt * SMAX;
    for (int i = tid; i < total; i += 256) gs[i] = sorted[i];
    if (tid < NPB) {
        g_cnt[bkt * NPB + tid] = cnt[tid];
        g_off[bkt * NPB + tid] = off[tid];
    }

    int dl   = tid >> 2;          // node in bucket (0..63)
    int sub  = tid & 3;
    int half = sub & 1;
    int part = sub >> 1;
    int node = (bkt << NPB_SH) + dl;
    bool act = node < N;          // no early return: barriers below

    int st = 0, nn = 0, fb = half * 8;
    if (act) {
        st = off[dl];
        nn = cnt[dl];
        if (st > SMAX) st = SMAX;
        if (st + nn > SMAX) nn = SMAX - st;
    }

    float a0 = 0.f, a1 = 0.f, a2 = 0.f, a3 = 0.f,
          a4 = 0.f, a5 = 0.f, a6 = 0.f, a7 = 0.f;
    GATHER2(p, sorted, st, nn, fb, part);
    PARITY_COMBINE();

    // h1 in f32 registers (mean + bias + root + relu), part==0 threads
    float h1v[8];
    if (act && part == 0) {
        float inv = 1.f / fmaxf((float)cnt[dl], 1.f);
        float4 qraw = *(const float4*)(q + (size_t)node * HID + fb);
        float2 q0 = __half22float2(*(const __half2*)&qraw.x);
        float2 q1 = __half22float2(*(const __half2*)&qraw.y);
        float2 q2v = __half22float2(*(const __half2*)&qraw.z);
        float2 q3 = __half22float2(*(const __half2*)&qraw.w);
        h1v[0] = fmaxf(a0*inv + b1[fb+0] + q0.x, 0.f);
        h1v[1] = fmaxf(a1*inv + b1[fb+1] + q0.y, 0.f);
        h1v[2] = fmaxf(a2*inv + b1[fb+2] + q1.x, 0.f);
        h1v[3] = fmaxf(a3*inv + b1[fb+3] + q1.y, 0.f);
        h1v[4] = fmaxf(a4*inv + b1[fb+4] + q2v.x, 0.f);
        h1v[5] = fmaxf(a5*inv + b1[fb+5] + q2v.y, 0.f);
        h1v[6] = fmaxf(a6*inv + b1[fb+6] + q3.x, 0.f);
        h1v[7] = fmaxf(a7*inv + b1[fb+7] + q3.y, 0.f);
    }
    __syncthreads();                    // all sorted[] reads complete

    // Stage h1 rows in LDS (alias sorted; stride 17 -> conflict-free)
    float* hl = (float*)sorted;         // 64*17 = 1088 floats < SMAX
    if (act && part == 0) {
        #pragma unroll
        for (int j = 0; j < 8; ++j) hl[dl * 17 + fb + j] = h1v[j];
    }
    __syncthreads();

    if (act && part == 0) {
        float hv[16];
        #pragma unroll
        for (int k = 0; k < HID; ++k) hv[k] = hl[dl * 17 + k];

        float accl[8], accr[8];
        #pragma unroll
        for (int f = 0; f < 8; ++f) { accl[f] = 0.f; accr[f] = 0.f; }
        #pragma unroll
        for (int k = 0; k < HID; ++k) {
            float hs = hv[k];
            #pragma unroll
            for (int f = 0; f < 8; ++f) {
                accl[f] = fmaf(hs, w2l[k * HID + fb + f], accl[f]);
                accr[f] = fmaf(hs, w2r[k * HID + fb + f], accr[f]);
            }
        }

        __half2 po[4], qo[4];
        #pragma unroll
        for (int f = 0; f < 4; ++f) {
            po[f] = __floats2half2_rn(accl[2*f], accl[2*f+1]);
            qo[f] = __floats2half2_rn(accr[2*f], accr[2*f+1]);
        }
        *(float4*)(p2 + (size_t)node * HID + fb) = *(float4*)&po[0];
        *(float4*)(q2 + (size_t)node * HID + fb) = *(float4*)&qo[0];
    }
}

// ---------------------------------------------------------------------------
// R8: agg#2 — sort-free (R5 structure, NPB=64, 4 threads/node).
// h may alias q (own-node row read-then-written by the same threads).
__global__ __launch_bounds__(256) void bucket_agg_reuse_kernel(
    const int* __restrict__ g_sorted, const int* __restrict__ g_cnt,
    const int* __restrict__ g_off,
    const __half* __restrict__ p, const __half* __restrict__ q,
    const float* __restrict__ b, __half* __restrict__ h, int N, int K)
{
    __shared__ int sorted[SMAX];
    __shared__ int cnt[NPB];
    __shared__ int off[NPB];

    int bkt = blockIdx.x;
    int tid = threadIdx.x;

    if (tid < NPB) {
        cnt[tid] = g_cnt[bkt * NPB + tid];
        off[tid] = g_off[bkt * NPB + tid];
    }
    __syncthreads();

    int total = off[NPB - 1] + cnt[NPB - 1];
    if (total > SMAX) total = SMAX;
    const int* gs = g_sorted + (size_t)bkt * SMAX;
    for (int i = tid; i < total; i += 256) sorted[i] = gs[i];
    __syncthreads();

    int dl   = tid >> 2;
    int sub  = tid & 3;
    int half = sub & 1;
    int part = sub >> 1;
    int node = (bkt << NPB_SH) + dl;
    bool act = node < N;

    int st = 0, nn = 0, fb = half * 8;
    if (act) {
        st = off[dl];
        nn = cnt[dl];
        if (st > SMAX) st = SMAX;
        if (st + nn > SMAX) nn = SMAX - st;
    }

    float a0 = 0.f, a1 = 0.f, a2 = 0.f, a3 = 0.f,
          a4 = 0.f, a5 = 0.f, a6 = 0.f, a7 = 0.f;
    GATHER2(p, sorted, st, nn, fb, part);
    PARITY_COMBINE();

    if (act && part == 0)
        agg_epilogue(a0, a1, a2, a3, a4, a5, a6, a7, cnt[dl], fb, node, q, b, h);
}

// ---------------------------------------------------------------------------
// MFMA edge MLP, transposed form. fc2 reduction via a SECOND MFMA (16x16x16).
__global__ __launch_bounds__(256) void edge_mlp_mfma_kernel(
    const int* __restrict__ src, const int* __restrict__ dst,
    const __half* __restrict__ h,
    const float* __restrict__ fc1w, const float* __restrict__ fc1b,
    const float* __restrict__ fc2w, const float* __restrict__ fc2b,
    float* __restrict__ out, int E, int ntiles)
{
    int lane   = threadIdx.x & 63;
    int wave   = (blockIdx.x * blockDim.x + threadIdx.x) >> 6;
    int nwaves = (gridDim.x * blockDim.x) >> 6;

    int n = lane & 15;      // edge within tile (B col, C col); also A row
    int q = lane >> 4;      // quad

    // fc1 A-fragment = W1^T: A[m=lane&15][k=q*8+j] = fc1w[(q*8+j)*16 + m]
    half8 wfrag;
    #pragma unroll
    for (int j = 0; j < 8; ++j)
        wfrag[j] = (_Float16)fc1w[(q * 8 + j) * 16 + n];

    // fc2 A-fragment (K=16): A[m=lane&15][k=q*4+j] = fc2w[(q*4+j)*2 + m], m<2
    half4 w2frag;
    #pragma unroll
    for (int j = 0; j < 4; ++j)
        w2frag[j] = (n < 2) ? (_Float16)fc2w[(q * 4 + j) * 2 + n]
                            : (_Float16)0.f;

    // fc1 bias for this lane's 4 z-rows (k = q*4+r)
    float bias1[4];
    #pragma unroll
    for (int r = 0; r < 4; ++r) bias1[r] = fc1b[q * 4 + r];
    float bb0 = fc2b[0], bb1 = fc2b[1];

    const int* tp = (q < 2) ? src : dst;
    int hoff = (q & 1) * 8;

    for (int t = wave; t < ntiles; t += nwaves) {
        int e   = t * 16 + n;
        int e_c = e < E ? e : E - 1;
        int idx = tp[e_c];
        half8 xf = *(const half8*)(h + (size_t)idx * HID + hoff);

        floatx4 acc = {0.f, 0.f, 0.f, 0.f};
        acc = __builtin_amdgcn_mfma_f32_16x16x32_f16(wfrag, xf, acc, 0, 0, 0);

        // z = relu(acc + b1) -> fp16 B-fragment for the fc2 MFMA
        half4 z;
        #pragma unroll
        for (int r = 0; r < 4; ++r)
            z[r] = (_Float16)fmaxf(acc[r] + bias1[r], 0.f);

        floatx4 acc2 = {0.f, 0.f, 0.f, 0.f};
        acc2 = __builtin_amdgcn_mfma_f32_16x16x16f16(w2frag, z, acc2, 0, 0, 0);

        if (q == 0) {
            int eo = t * 16 + n;
            if (eo < E) {
                float a  = acc2[0] + bb0;
                float c  = acc2[1] + bb1;
                float mx = fmaxf(a, c);
                float lse = mx + __logf(__expf(a - mx) + __expf(c - mx));
                ((float2*)out)[eo] = make_float2(a - lse, c - lse);
            }
        }
    }
}

// ---------------------------------------------------------------------------
extern "C" void kernel_launch(void* const* d_in, const int* in_sizes, int n_in,
                              void* d_out, int out_size, void* d_ws, size_t ws_size,
                              hipStream_t stream)
{
    const float* x    = (const float*)d_in[0];
    const int*   ei   = (const int*)  d_in[1];
    const float* w1l  = (const float*)d_in[2];
    const float* b1l  = (const float*)d_in[3];
    const float* w1r  = (const float*)d_in[4];
    const float* w2l  = (const float*)d_in[5];
    const float* b2l  = (const float*)d_in[6];
    const float* w2r  = (const float*)d_in[7];
    const float* fc1w = (const float*)d_in[8];
    const float* fc1b = (const float*)d_in[9];
    const float* fc2w = (const float*)d_in[10];
    const float* fc2b = (const float*)d_in[11];
    float* out = (float*)d_out;

    int N = in_sizes[0] / NF;
    int E = in_sizes[1] / 2;
    const int* src = ei;
    const int* dst = ei + E;

    int K = (N + NPB - 1) / NPB;   // 1563 buckets (<= KMAX)

    // ws: A16|B16|C16|D16 | recs | cursor | ovf_cnt | ovf | g_sorted|g_cnt|g_off
    __half* A16      = (__half*)d_ws;            // p1
    __half* B16      = A16 + (size_t)N * HID;    // q1
    __half* C16      = B16 + (size_t)N * HID;    // p2
    __half* D16      = C16 + (size_t)N * HID;    // q2 -> h2 (in-place)
    int*    recs     = (int*)(D16 + (size_t)N * HID);
    int*    cursor   = recs + (size_t)NXCD * K * CAP;
    int*    ovfcnt   = cursor + (size_t)NXCD * K;
    int2*   ovf      = (int2*)(ovfcnt + 2);
    int*    g_sorted = (int*)(ovf + OVF_CAP);
    int*    g_cnt    = g_sorted + (size_t)K * SMAX;
    int*    g_off    = g_cnt + (size_t)K * NPB;

    int ncur = NXCD * K + 1;

    zero_kernel<<<(ncur + 255) / 256, 256, 0, stream>>>(cursor, ncur);
    scatter_bin_kernel<<<(E + CH - 1) / CH, 256, 0, stream>>>(src, dst, cursor, recs,
                                                              ovfcnt, ovf, E, K);

    int ntiles_n = (N + 15) / 16;            // 6250
    int gemm_blocks = (ntiles_n + 7) / 8;    // 2 tiles per wave, balanced

    gemm1_kernel<<<gemm_blocks, 256, 0, stream>>>(x, w1l, w1r, A16, B16, N, ntiles_n);

    // agg#1 fused with gemm2: h1 never hits global; writes p2->C16, q2->D16
    bucket_agg1_fused_kernel<<<K, 256, 0, stream>>>(cursor, recs, ovfcnt, ovf,
                                                    A16, B16, b1l, w2l, w2r,
                                                    C16, D16, N, K,
                                                    g_sorted, g_cnt, g_off);

    // agg#2: h2 = relu(mean(p2)+b2+q2), in-place over D16
    bucket_agg_reuse_kernel<<<K, 256, 0, stream>>>(g_sorted, g_cnt, g_off,
                                                   C16, D16, b2l, D16, N, K);

    int ntiles = (E + 15) / 16;
    edge_mlp_mfma_kernel<<<2048, 256, 0, stream>>>(src, dst, D16, fc1w, fc1b,
                                                   fc2w, fc2b, out, E, ntiles);
}

// Round 9
// 265.607 us; speedup vs baseline: 1.0891x; 1.0494x over previous
//
#include <hip/hip_runtime.h>
#include <hip/hip_fp16.h>
#include <math.h>

#define NF   128
#define HID  16
#define NPB  128          // nodes per bucket (dst >> 7)
#define CAP  768          // records per (xcd, bucket) cell; mean 511
#define NXCD 8
#define SMAX (NXCD * CAP) // max records per bucket in LDS sort (6144)
#define OVF_CAP 262144    // statistically-unreachable overflow list
#define KMAX 1024         // max buckets (N <= 131072)
#define CH   2048         // edges per block in scatter_bin (8/thread, reg-cached)

typedef _Float16 half8 __attribute__((ext_vector_type(8)));
typedef _Float16 half4 __attribute__((ext_vector_type(4)));
typedef float    floatx4 __attribute__((ext_vector_type(4)));

// ---------------------------------------------------------------------------
__global__ void zero_kernel(int* __restrict__ ptr, int n) {
    int i = blockIdx.x * blockDim.x + threadIdx.x;
    if (i < n) ptr[i] = 0;
}

// ---------------------------------------------------------------------------
// R9: FRONT kernel — scatter_bin and gemm1 are data-independent (edges vs x),
// so they share one dispatch with disjoint blockIdx ranges. Latency-bound
// scatter waves and compute-dense gemm waves co-schedule on each CU.
// Blocks [0, SB): scatter_bin body (byte-identical to R5's kernel).
// Blocks [SB, SB+GB): gemm1 MFMA body (byte-identical to R5's kernel).
__global__ __launch_bounds__(256, 4) void front_kernel(
    const int* __restrict__ src, const int* __restrict__ dst,
    int* __restrict__ cursor, int* __restrict__ recs,
    int* __restrict__ ovf_cnt, int2* __restrict__ ovf, int E, int K,
    const float* __restrict__ x, const float* __restrict__ wl,
    const float* __restrict__ wr, __half* __restrict__ p,
    __half* __restrict__ q, int N, int ntiles, int SB)
{
    __shared__ int cnt[KMAX];
    __shared__ int resbase[KMAX];
    __shared__ int cur[KMAX];

    int tid = threadIdx.x;

    if ((int)blockIdx.x < SB) {
        // ---------------- scatter_bin ----------------
        int base = blockIdx.x * CH;

        for (int b = tid; b < K; b += 256) cnt[b] = 0;
        __syncthreads();

        int ebase = base + tid * 8;
        int4 da = {0,0,0,0}, db = {0,0,0,0}, sa = {0,0,0,0}, sb = {0,0,0,0};
        if (ebase + 8 <= E) {
            da = ((const int4*)(dst + ebase))[0];
            db = ((const int4*)(dst + ebase))[1];
            sa = ((const int4*)(src + ebase))[0];
            sb = ((const int4*)(src + ebase))[1];
        } else if (ebase < E) {
            int m = E - ebase;
            if (m > 0) { da.x = dst[ebase+0]; sa.x = src[ebase+0]; }
            if (m > 1) { da.y = dst[ebase+1]; sa.y = src[ebase+1]; }
            if (m > 2) { da.z = dst[ebase+2]; sa.z = src[ebase+2]; }
            if (m > 3) { da.w = dst[ebase+3]; sa.w = src[ebase+3]; }
            if (m > 4) { db.x = dst[ebase+4]; sb.x = src[ebase+4]; }
            if (m > 5) { db.y = dst[ebase+5]; sb.y = src[ebase+5]; }
            if (m > 6) { db.z = dst[ebase+6]; sb.z = src[ebase+6]; }
        }
        int ne = E - ebase; ne = ne < 0 ? 0 : (ne > 8 ? 8 : ne);
        int d[8] = {da.x, da.y, da.z, da.w, db.x, db.y, db.z, db.w};
        int s[8] = {sa.x, sa.y, sa.z, sa.w, sb.x, sb.y, sb.z, sb.w};

        #pragma unroll
        for (int i = 0; i < 8; ++i)
            if (i < ne) atomicAdd(&cnt[((unsigned)d[i]) >> 7], 1);
        __syncthreads();

        int xcd;
        asm volatile("s_getreg_b32 %0, hwreg(HW_REG_XCC_ID)" : "=s"(xcd));
        xcd &= 7;

        for (int b = tid; b < K; b += 256) {
            int c = cnt[b];
            cur[b] = 0;
            if (c > 0)
                resbase[b] = __hip_atomic_fetch_add(&cursor[xcd * K + b], c,
                                                    __ATOMIC_RELAXED,
                                                    __HIP_MEMORY_SCOPE_WORKGROUP);
        }
        __syncthreads();

        #pragma unroll
        for (int i = 0; i < 8; ++i) {
            if (i >= ne) break;
            int b = ((unsigned)d[i]) >> 7;
            int idx  = atomicAdd(&cur[b], 1);          // LDS
            int slot = resbase[b] + idx;
            if (slot < CAP) {
                recs[((size_t)(xcd * K + b)) * CAP + slot] =
                    ((d[i] & 127) << 17) | s[i];
            } else {
                int op = atomicAdd(ovf_cnt, 1);        // device scope; ~never
                if (op < OVF_CAP) ovf[op] = make_int2(d[i], s[i]);
            }
        }
    } else {
        // ---------------- gemm1 (MFMA) ----------------
        int lane   = tid & 63;
        int wave   = (((int)blockIdx.x - SB) * 256 + tid) >> 6;
        int nwaves = ((gridDim.x - SB) * 256) >> 6;

        int m  = lane & 15;   // A row (feature) / B col (node) / C col (node)
        int qd = lane >> 4;   // quad

        half8 wlh[4], wll[4], wrh[4], wrl[4];
        #pragma unroll
        for (int kk = 0; kk < 4; ++kk) {
            #pragma unroll
            for (int j = 0; j < 8; ++j) {
                int k = kk * 32 + qd * 8 + j;
                float a = wl[k * HID + m];
                _Float16 ah = (_Float16)a;
                wlh[kk][j] = ah;
                wll[kk][j] = (_Float16)(a - (float)ah);
                float b = wr[k * HID + m];
                _Float16 bh = (_Float16)b;
                wrh[kk][j] = bh;
                wrl[kk][j] = (_Float16)(b - (float)bh);
            }
        }

        for (int t = wave; t < ntiles; t += nwaves) {
            int node = t * 16 + m;
            int nc   = node < N ? node : N - 1;
            const float4* xr = (const float4*)(x + (size_t)nc * NF);

            floatx4 accl = {0.f, 0.f, 0.f, 0.f};
            floatx4 accr = {0.f, 0.f, 0.f, 0.f};

            #pragma unroll
            for (int kk = 0; kk < 4; ++kk) {
                float4 v0 = xr[kk * 8 + qd * 2 + 0];
                float4 v1 = xr[kk * 8 + qd * 2 + 1];
                float xs[8] = {v0.x, v0.y, v0.z, v0.w, v1.x, v1.y, v1.z, v1.w};
                half8 xh, xlo;
                #pragma unroll
                for (int j = 0; j < 8; ++j) {
                    _Float16 hh = (_Float16)xs[j];
                    xh[j]  = hh;
                    xlo[j] = (_Float16)(xs[j] - (float)hh);
                }
                accl = __builtin_amdgcn_mfma_f32_16x16x32_f16(wlh[kk], xh,  accl, 0, 0, 0);
                accr = __builtin_amdgcn_mfma_f32_16x16x32_f16(wrh[kk], xh,  accr, 0, 0, 0);
                accl = __builtin_amdgcn_mfma_f32_16x16x32_f16(wll[kk], xh,  accl, 0, 0, 0);
                accr = __builtin_amdgcn_mfma_f32_16x16x32_f16(wrl[kk], xh,  accr, 0, 0, 0);
                accl = __builtin_amdgcn_mfma_f32_16x16x32_f16(wlh[kk], xlo, accl, 0, 0, 0);
                accr = __builtin_amdgcn_mfma_f32_16x16x32_f16(wrh[kk], xlo, accr, 0, 0, 0);
            }

            if (node < N) {
                float2 pv, qv;
                *(__half2*)&pv.x = __floats2half2_rn(accl[0], accl[1]);
                *(__half2*)&pv.y = __floats2half2_rn(accl[2], accl[3]);
                *(__half2*)&qv.x = __floats2half2_rn(accr[0], accr[1]);
                *(__half2*)&qv.y = __floats2half2_rn(accr[2], accr[3]);
                *(float2*)(p + (size_t)node * HID + qd * 4) = pv;
                *(float2*)(q + (size_t)node * HID + qd * 4) = qv;
            }
        }
    }
}

// ---------------------------------------------------------------------------
// Accumulate helper: 8 features from a 16B half-row.
#define ACC8(raw)                                                      \
    {                                                                  \
        float2 v0 = __half22float2(*(const __half2*)&(raw).x);         \
        float2 v1 = __half22float2(*(const __half2*)&(raw).y);         \
        float2 v2 = __half22float2(*(const __half2*)&(raw).z);         \
        float2 v3 = __half22float2(*(const __half2*)&(raw).w);         \
        a0 += v0.x; a1 += v0.y; a2 += v1.x; a3 += v1.y;                \
        a4 += v2.x; a5 += v2.y; a6 += v3.x; a7 += v3.y;                \
    }

// 8-deep unrolled gather-accumulate over sorted[st..st+n) from p rows.
#define GATHER_LOOP(p_, sorted_, st_, n_, fb_)                         \
    {                                                                  \
        int i = 0;                                                     \
        for (; i + 8 <= (n_); i += 8) {                                \
            int s0 = (sorted_)[(st_) + i + 0], s1 = (sorted_)[(st_) + i + 1]; \
            int s2 = (sorted_)[(st_) + i + 2], s3 = (sorted_)[(st_) + i + 3]; \
            int s4 = (sorted_)[(st_) + i + 4], s5 = (sorted_)[(st_) + i + 5]; \
            int s6 = (sorted_)[(st_) + i + 6], s7 = (sorted_)[(st_) + i + 7]; \
            float4 r0 = *(const float4*)((p_) + (size_t)s0 * HID + (fb_)); \
            float4 r1 = *(const float4*)((p_) + (size_t)s1 * HID + (fb_)); \
            float4 r2 = *(const float4*)((p_) + (size_t)s2 * HID + (fb_)); \
            float4 r3 = *(const float4*)((p_) + (size_t)s3 * HID + (fb_)); \
            float4 r4 = *(const float4*)((p_) + (size_t)s4 * HID + (fb_)); \
            float4 r5 = *(const float4*)((p_) + (size_t)s5 * HID + (fb_)); \
            float4 r6 = *(const float4*)((p_) + (size_t)s6 * HID + (fb_)); \
            float4 r7 = *(const float4*)((p_) + (size_t)s7 * HID + (fb_)); \
            ACC8(r0); ACC8(r1); ACC8(r2); ACC8(r3);                    \
            ACC8(r4); ACC8(r5); ACC8(r6); ACC8(r7);                    \
        }                                                              \
        for (; i < (n_); ++i) {                                        \
            int s = (sorted_)[(st_) + i];                              \
            float4 raw = *(const float4*)((p_) + (size_t)s * HID + (fb_)); \
            ACC8(raw);                                                 \
        }                                                              \
    }

// Shared epilogue: mean + bias + root + relu -> h
__device__ __forceinline__ void agg_epilogue(
    float a0, float a1, float a2, float a3,
    float a4, float a5, float a6, float a7,
    int n_cnt, int fb, int node,
    const __half* __restrict__ q, const float* __restrict__ b,
    __half* __restrict__ h)
{
    float inv = 1.f / fmaxf((float)n_cnt, 1.f);
    float4 qraw = *(const float4*)(q + (size_t)node * HID + fb);
    float2 q0 = __half22float2(*(const __half2*)&qraw.x);
    float2 q1 = __half22float2(*(const __half2*)&qraw.y);
    float2 q2 = __half22float2(*(const __half2*)&qraw.z);
    float2 q3 = __half22float2(*(const __half2*)&qraw.w);

    __half2 r0 = __floats2half2_rn(fmaxf(a0*inv + b[fb+0] + q0.x, 0.f),
                                   fmaxf(a1*inv + b[fb+1] + q0.y, 0.f));
    __half2 r1 = __floats2half2_rn(fmaxf(a2*inv + b[fb+2] + q1.x, 0.f),
                                   fmaxf(a3*inv + b[fb+3] + q1.y, 0.f));
    __half2 r2 = __floats2half2_rn(fmaxf(a4*inv + b[fb+4] + q2.x, 0.f),
                                   fmaxf(a5*inv + b[fb+5] + q2.y, 0.f));
    __half2 r3 = __floats2half2_rn(fmaxf(a6*inv + b[fb+6] + q3.x, 0.f),
                                   fmaxf(a7*inv + b[fb+7] + q3.y, 0.f));
    float4 res;
    *(__half2*)&res.x = r0; *(__half2*)&res.y = r1;
    *(__half2*)&res.z = r2; *(__half2*)&res.w = r3;
    *(float4*)(h + (size_t)node * HID + fb) = res;
}

// ---------------------------------------------------------------------------
// R5/R9: agg#1 FUSED with gemm2. In-LDS counting sort + CSR persist + gather,
// then h1 = relu(mean+b1+q1) stays in registers/LDS (f32, never written to
// global) and the 16x16 W2l/W2r matvec runs in the epilogue, writing
// p2 -> C16, q2 -> D16.
__global__ __launch_bounds__(256) void bucket_agg1_fused_kernel(
    const int* __restrict__ cursor, const int* __restrict__ recs,
    const int* __restrict__ ovf_cnt, const int2* __restrict__ ovf,
    const __half* __restrict__ p, const __half* __restrict__ q,
    const float* __restrict__ b1,
    const float* __restrict__ w2l, const float* __restrict__ w2r,
    __half* __restrict__ p2, __half* __restrict__ q2, int N, int K,
    int* __restrict__ g_sorted, int* __restrict__ g_cnt,
    int* __restrict__ g_off)
{
    __shared__ int sorted[SMAX];
    __shared__ int cnt[NPB];
    __shared__ int off[NPB];
    __shared__ int cur[NPB];
    __shared__ int scan[NPB];
    __shared__ int s_ovf;

    int bkt = blockIdx.x;
    int tid = threadIdx.x;

    if (tid < NPB) cnt[tid] = 0;
    if (tid == 0) { int v = *ovf_cnt; s_ovf = v < OVF_CAP ? v : OVF_CAP; }
    __syncthreads();

    for (int xcd = 0; xcd < NXCD; ++xcd) {
        int cell = xcd * K + bkt;
        int len = cursor[cell]; if (len > CAP) len = CAP;
        const int* cr = recs + (size_t)cell * CAP;
        for (int r = tid; r < len; r += 256)
            atomicAdd(&cnt[((unsigned)cr[r]) >> 17], 1);
    }
    if (s_ovf > 0) {
        for (int r = tid; r < s_ovf; r += 256) {
            int2 od = ovf[r];
            if ((od.x >> 7) == bkt) atomicAdd(&cnt[od.x & 127], 1);
        }
    }
    __syncthreads();

    if (tid < NPB) scan[tid] = cnt[tid];
    __syncthreads();
    for (int o = 1; o < NPB; o <<= 1) {
        int v = 0;
        if (tid < NPB && tid >= o) v = scan[tid - o];
        __syncthreads();
        if (tid < NPB) scan[tid] += v;
        __syncthreads();
    }
    if (tid < NPB) { int e = scan[tid] - cnt[tid]; off[tid] = e; cur[tid] = e; }
    __syncthreads();

    for (int xcd = 0; xcd < NXCD; ++xcd) {
        int cell = xcd * K + bkt;
        int len = cursor[cell]; if (len > CAP) len = CAP;
        const int* cr = recs + (size_t)cell * CAP;
        for (int r = tid; r < len; r += 256) {
            int rec = cr[r];
            int slot = atomicAdd(&cur[((unsigned)rec) >> 17], 1);
            if (slot < SMAX) sorted[slot] = rec & 0x1FFFF;
        }
    }
    if (s_ovf > 0) {
        for (int r = tid; r < s_ovf; r += 256) {
            int2 od = ovf[r];
            if ((od.x >> 7) == bkt) {
                int slot = atomicAdd(&cur[od.x & 127], 1);
                if (slot < SMAX) sorted[slot] = od.y;
            }
        }
    }
    __syncthreads();

    // Persist CSR for the second aggregation pass.
    int total = off[NPB - 1] + cnt[NPB - 1];
    if (total > SMAX) total = SMAX;
    int* gs = g_sorted + (size_t)bkt * SMAX;
    for (int i = tid; i < total; i += 256) gs[i] = sorted[i];
    if (tid < NPB) {
        g_cnt[bkt * NPB + tid] = cnt[tid];
        g_off[bkt * NPB + tid] = off[tid];
    }

    int dl   = tid >> 1;
    int half = tid & 1;
    int node = (bkt << 7) + dl;
    bool act = node < N;                // no early return: barriers below

    int st = 0, nn = 0, fb = half * 8;
    if (act) {
        st = off[dl];
        nn = cnt[dl];
        if (st > SMAX) st = SMAX;
        if (st + nn > SMAX) nn = SMAX - st;
    }

    float a0 = 0.f, a1 = 0.f, a2 = 0.f, a3 = 0.f,
          a4 = 0.f, a5 = 0.f, a6 = 0.f, a7 = 0.f;
    GATHER_LOOP(p, sorted, st, nn, fb);

    // h1 in f32 registers (mean + bias + root + relu)
    float h1v[8];
    if (act) {
        float inv = 1.f / fmaxf((float)cnt[dl], 1.f);
        float4 qraw = *(const float4*)(q + (size_t)node * HID + fb);
        float2 q0 = __half22float2(*(const __half2*)&qraw.x);
        float2 q1 = __half22float2(*(const __half2*)&qraw.y);
        float2 q2v = __half22float2(*(const __half2*)&qraw.z);
        float2 q3 = __half22float2(*(const __half2*)&qraw.w);
        h1v[0] = fmaxf(a0*inv + b1[fb+0] + q0.x, 0.f);
        h1v[1] = fmaxf(a1*inv + b1[fb+1] + q0.y, 0.f);
        h1v[2] = fmaxf(a2*inv + b1[fb+2] + q1.x, 0.f);
        h1v[3] = fmaxf(a3*inv + b1[fb+3] + q1.y, 0.f);
        h1v[4] = fmaxf(a4*inv + b1[fb+4] + q2v.x, 0.f);
        h1v[5] = fmaxf(a5*inv + b1[fb+5] + q2v.y, 0.f);
        h1v[6] = fmaxf(a6*inv + b1[fb+6] + q3.x, 0.f);
        h1v[7] = fmaxf(a7*inv + b1[fb+7] + q3.y, 0.f);
    }
    __syncthreads();                    // all sorted[] reads complete

    // Stage h1 rows in LDS (alias sorted; stride 17 -> conflict-free)
    float* hl = (float*)sorted;         // needs 128*17 = 2176 floats < SMAX
    if (act) {
        #pragma unroll
        for (int j = 0; j < 8; ++j) hl[dl * 17 + fb + j] = h1v[j];
    }
    __syncthreads();

    if (act) {
        float hv[16];
        #pragma unroll
        for (int k = 0; k < HID; ++k) hv[k] = hl[dl * 17 + k];

        float accl[8], accr[8];
        #pragma unroll
        for (int f = 0; f < 8; ++f) { accl[f] = 0.f; accr[f] = 0.f; }
        #pragma unroll
        for (int k = 0; k < HID; ++k) {
            float hs = hv[k];
            #pragma unroll
            for (int f = 0; f < 8; ++f) {
                accl[f] = fmaf(hs, w2l[k * HID + fb + f], accl[f]);
                accr[f] = fmaf(hs, w2r[k * HID + fb + f], accr[f]);
            }
        }

        __half2 po[4], qo[4];
        #pragma unroll
        for (int f = 0; f < 4; ++f) {
            po[f] = __floats2half2_rn(accl[2*f], accl[2*f+1]);
            qo[f] = __floats2half2_rn(accr[2*f], accr[2*f+1]);
        }
        *(float4*)(p2 + (size_t)node * HID + fb) = *(float4*)&po[0];
        *(float4*)(q2 + (size_t)node * HID + fb) = *(float4*)&qo[0];
    }
}

// ---------------------------------------------------------------------------
// R5/R9: agg#2 — sort-free. Loads persisted CSR into LDS, 8-way unrolled
// gather-accumulate. h may alias q (own-bucket rows only, read-then-write).
__global__ __launch_bounds__(256) void bucket_agg_reuse_kernel(
    const int* __restrict__ g_sorted, const int* __restrict__ g_cnt,
    const int* __restrict__ g_off,
    const __half* __restrict__ p, const __half* __restrict__ q,
    const float* __restrict__ b, __half* __restrict__ h, int N, int K)
{
    __shared__ int sorted[SMAX];
    __shared__ int cnt[NPB];
    __shared__ int off[NPB];

    int bkt = blockIdx.x;
    int tid = threadIdx.x;

    if (tid < NPB) {
        cnt[tid] = g_cnt[bkt * NPB + tid];
        off[tid] = g_off[bkt * NPB + tid];
    }
    __syncthreads();

    int total = off[NPB - 1] + cnt[NPB - 1];
    if (total > SMAX) total = SMAX;
    const int* gs = g_sorted + (size_t)bkt * SMAX;
    for (int i = tid; i < total; i += 256) sorted[i] = gs[i];
    __syncthreads();

    int dl   = tid >> 1;
    int half = tid & 1;
    int node = (bkt << 7) + dl;
    if (node >= N) return;

    int st = off[dl];
    int n  = cnt[dl];
    if (st > SMAX) st = SMAX;
    if (st + n > SMAX) n = SMAX - st;
    int fb = half * 8;

    float a0 = 0.f, a1 = 0.f, a2 = 0.f, a3 = 0.f,
          a4 = 0.f, a5 = 0.f, a6 = 0.f, a7 = 0.f;
    GATHER_LOOP(p, sorted, st, n, fb);

    agg_epilogue(a0, a1, a2, a3, a4, a5, a6, a7, cnt[dl], fb, node, q, b, h);
}

// ---------------------------------------------------------------------------
// MFMA edge MLP, transposed form. fc2 reduction via a SECOND MFMA
// (16x16x16): the first MFMA's C layout (lane(q,n) holds Z[k=q*4+r][edge n])
// is exactly the K=16 B-fragment layout; A = W2^T zero-padded to 16 rows.
// Lanes q==0 get both class logits in acc2[0..1] and store coalesced float2.
__global__ __launch_bounds__(256) void edge_mlp_mfma_kernel(
    const int* __restrict__ src, const int* __restrict__ dst,
    const __half* __restrict__ h,
    const float* __restrict__ fc1w, const float* __restrict__ fc1b,
    const float* __restrict__ fc2w, const float* __restrict__ fc2b,
    float* __restrict__ out, int E, int ntiles)
{
    int lane   = threadIdx.x & 63;
    int wave   = (blockIdx.x * blockDim.x + threadIdx.x) >> 6;
    int nwaves = (gridDim.x * blockDim.x) >> 6;

    int n = lane & 15;      // edge within tile (B col, C col); also A row
    int q = lane >> 4;      // quad

    // fc1 A-fragment = W1^T: A[m=lane&15][k=q*8+j] = fc1w[(q*8+j)*16 + m]
    half8 wfrag;
    #pragma unroll
    for (int j = 0; j < 8; ++j)
        wfrag[j] = (_Float16)fc1w[(q * 8 + j) * 16 + n];

    // fc2 A-fragment (K=16): A[m=lane&15][k=q*4+j] = fc2w[(q*4+j)*2 + m], m<2
    half4 w2frag;
    #pragma unroll
    for (int j = 0; j < 4; ++j)
        w2frag[j] = (n < 2) ? (_Float16)fc2w[(q * 4 + j) * 2 + n]
                            : (_Float16)0.f;

    // fc1 bias for this lane's 4 z-rows (k = q*4+r)
    float bias1[4];
    #pragma unroll
    for (int r = 0; r < 4; ++r) bias1[r] = fc1b[q * 4 + r];
    float bb0 = fc2b[0], bb1 = fc2b[1];

    const int* tp = (q < 2) ? src : dst;
    int hoff = (q & 1) * 8;

    for (int t = wave; t < ntiles; t += nwaves) {
        int e   = t * 16 + n;
        int e_c = e < E ? e : E - 1;
        int idx = tp[e_c];
        half8 xf = *(const half8*)(h + (size_t)idx * HID + hoff);

        floatx4 acc = {0.f, 0.f, 0.f, 0.f};
        acc = __builtin_amdgcn_mfma_f32_16x16x32_f16(wfrag, xf, acc, 0, 0, 0);

        // z = relu(acc + b1) -> fp16 B-fragment for the fc2 MFMA
        half4 z;
        #pragma unroll
        for (int r = 0; r < 4; ++r)
            z[r] = (_Float16)fmaxf(acc[r] + bias1[r], 0.f);

        floatx4 acc2 = {0.f, 0.f, 0.f, 0.f};
        acc2 = __builtin_amdgcn_mfma_f32_16x16x16f16(w2frag, z, acc2, 0, 0, 0);

        if (q == 0) {
            int eo = t * 16 + n;
            if (eo < E) {
                float a  = acc2[0] + bb0;
                float c  = acc2[1] + bb1;
                float mx = fmaxf(a, c);
                float lse = mx + __logf(__expf(a - mx) + __expf(c - mx));
                ((float2*)out)[eo] = make_float2(a - lse, c - lse);
            }
        }
    }
}

// ---------------------------------------------------------------------------
extern "C" void kernel_launch(void* const* d_in, const int* in_sizes, int n_in,
                              void* d_out, int out_size, void* d_ws, size_t ws_size,
                              hipStream_t stream)
{
    const float* x    = (const float*)d_in[0];
    const int*   ei   = (const int*)  d_in[1];
    const float* w1l  = (const float*)d_in[2];
    const float* b1l  = (const float*)d_in[3];
    const float* w1r  = (const float*)d_in[4];
    const float* w2l  = (const float*)d_in[5];
    const float* b2l  = (const float*)d_in[6];
    const float* w2r  = (const float*)d_in[7];
    const float* fc1w = (const float*)d_in[8];
    const float* fc1b = (const float*)d_in[9];
    const float* fc2w = (const float*)d_in[10];
    const float* fc2b = (const float*)d_in[11];
    float* out = (float*)d_out;

    int N = in_sizes[0] / NF;
    int E = in_sizes[1] / 2;
    const int* src = ei;
    const int* dst = ei + E;

    int K = (N + NPB - 1) / NPB;   // 782 buckets (<= KMAX)

    // ws: A16|B16|C16|D16 | recs | cursor | ovf_cnt | ovf | g_sorted|g_cnt|g_off
    __half* A16      = (__half*)d_ws;            // p1
    __half* B16      = A16 + (size_t)N * HID;    // q1
    __half* C16      = B16 + (size_t)N * HID;    // p2
    __half* D16      = C16 + (size_t)N * HID;    // q2 -> h2 (in-place)
    int*    recs     = (int*)(D16 + (size_t)N * HID);
    int*    cursor   = recs + (size_t)NXCD * K * CAP;
    int*    ovfcnt   = cursor + (size_t)NXCD * K;
    int2*   ovf      = (int2*)(ovfcnt + 2);
    int*    g_sorted = (int*)(ovf + OVF_CAP);
    int*    g_cnt    = g_sorted + (size_t)K * SMAX;
    int*    g_off    = g_cnt + (size_t)K * NPB;

    int ncur = NXCD * K + 1;

    zero_kernel<<<(ncur + 255) / 256, 256, 0, stream>>>(cursor, ncur);

    // Fused front: scatter_bin (SB blocks) + gemm1 (GB blocks) — independent
    int SB = (E + CH - 1) / CH;              // 1563 scatter blocks
    int ntiles_n = (N + 15) / 16;            // 6250
    int GB = (ntiles_n + 7) / 8;             // 782 gemm blocks (2 tiles/wave)
    front_kernel<<<SB + GB, 256, 0, stream>>>(src, dst, cursor, recs,
                                              ovfcnt, ovf, E, K,
                                              x, w1l, w1r, A16, B16, N,
                                              ntiles_n, SB);

    // agg#1 fused with gemm2: h1 never hits global; writes p2->C16, q2->D16
    bucket_agg1_fused_kernel<<<K, 256, 0, stream>>>(cursor, recs, ovfcnt, ovf,
                                                    A16, B16, b1l, w2l, w2r,
                                                    C16, D16, N, K,
                                                    g_sorted, g_cnt, g_off);

    // agg#2: h2 = relu(mean(p2)+b2+q2), in-place over D16
    bucket_agg_reuse_kernel<<<K, 256, 0, stream>>>(g_sorted, g_cnt, g_off,
                                                   C16, D16, b2l, D16, N, K);

    int ntiles = (E + 15) / 16;
    edge_mlp_mfma_kernel<<<2048, 256, 0, stream>>>(src, dst, D16, fc1w, fc1b,
                                                   fc2w, fc2b, out, E, ntiles);
}

// Round 10
// 262.094 us; speedup vs baseline: 1.1037x; 1.0134x over previous
//
#include <hip/hip_runtime.h>
#include <hip/hip_fp16.h>
#include <math.h>

#define NF   128
#define HID  16
#define NPB  128          // nodes per bucket (dst >> 7)
#define CAP  768          // records per (xcd, bucket) cell; mean 511
#define NXCD 8
#define SMAX (NXCD * CAP) // max records per bucket in LDS sort (6144)
#define OVF_CAP 262144    // statistically-unreachable overflow list
#define KMAX 1024         // max buckets (N <= 131072)
#define CH   2048         // edges per block in scatter_bin (8/thread, reg-cached)

typedef _Float16 half8 __attribute__((ext_vector_type(8)));
typedef _Float16 half4 __attribute__((ext_vector_type(4)));
typedef float    floatx4 __attribute__((ext_vector_type(4)));

// ---------------------------------------------------------------------------
__global__ void zero_kernel(int* __restrict__ ptr, int n) {
    int i = blockIdx.x * blockDim.x + threadIdx.x;
    if (i < n) ptr[i] = 0;
}

// ---------------------------------------------------------------------------
// Block-chunked two-pass binning: LDS histogram -> one XCD-local L2 atomic
// per touched bucket -> private contiguous range fill.
// Record = (dst & 127) << 17 | src   (src < 2^17).
__global__ __launch_bounds__(256) void scatter_bin_kernel(
    const int* __restrict__ src, const int* __restrict__ dst,
    int* __restrict__ cursor, int* __restrict__ recs,
    int* __restrict__ ovf_cnt, int2* __restrict__ ovf, int E, int K)
{
    __shared__ int cnt[KMAX];
    __shared__ int resbase[KMAX];
    __shared__ int cur[KMAX];

    int tid  = threadIdx.x;
    int base = blockIdx.x * CH;

    for (int b = tid; b < K; b += 256) cnt[b] = 0;
    __syncthreads();

    int ebase = base + tid * 8;
    int4 da = {0,0,0,0}, db = {0,0,0,0}, sa = {0,0,0,0}, sb = {0,0,0,0};
    if (ebase + 8 <= E) {
        da = ((const int4*)(dst + ebase))[0];
        db = ((const int4*)(dst + ebase))[1];
        sa = ((const int4*)(src + ebase))[0];
        sb = ((const int4*)(src + ebase))[1];
    } else if (ebase < E) {
        int m = E - ebase;
        if (m > 0) { da.x = dst[ebase+0]; sa.x = src[ebase+0]; }
        if (m > 1) { da.y = dst[ebase+1]; sa.y = src[ebase+1]; }
        if (m > 2) { da.z = dst[ebase+2]; sa.z = src[ebase+2]; }
        if (m > 3) { da.w = dst[ebase+3]; sa.w = src[ebase+3]; }
        if (m > 4) { db.x = dst[ebase+4]; sb.x = src[ebase+4]; }
        if (m > 5) { db.y = dst[ebase+5]; sb.y = src[ebase+5]; }
        if (m > 6) { db.z = dst[ebase+6]; sb.z = src[ebase+6]; }
    }
    int ne = E - ebase; ne = ne < 0 ? 0 : (ne > 8 ? 8 : ne);
    int d[8] = {da.x, da.y, da.z, da.w, db.x, db.y, db.z, db.w};
    int s[8] = {sa.x, sa.y, sa.z, sa.w, sb.x, sb.y, sb.z, sb.w};

    #pragma unroll
    for (int i = 0; i < 8; ++i)
        if (i < ne) atomicAdd(&cnt[((unsigned)d[i]) >> 7], 1);
    __syncthreads();

    int xcd;
    asm volatile("s_getreg_b32 %0, hwreg(HW_REG_XCC_ID)" : "=s"(xcd));
    xcd &= 7;

    for (int b = tid; b < K; b += 256) {
        int c = cnt[b];
        cur[b] = 0;
        if (c > 0)
            resbase[b] = __hip_atomic_fetch_add(&cursor[xcd * K + b], c,
                                                __ATOMIC_RELAXED,
                                                __HIP_MEMORY_SCOPE_WORKGROUP);
    }
    __syncthreads();

    #pragma unroll
    for (int i = 0; i < 8; ++i) {
        if (i >= ne) break;
        int b = ((unsigned)d[i]) >> 7;
        int idx  = atomicAdd(&cur[b], 1);          // LDS
        int slot = resbase[b] + idx;
        if (slot < CAP) {
            recs[((size_t)(xcd * K + b)) * CAP + slot] = ((d[i] & 127) << 17) | s[i];
        } else {
            int op = atomicAdd(ovf_cnt, 1);        // device scope; ~never
            if (op < OVF_CAP) ovf[op] = make_int2(d[i], s[i]);
        }
    }
}

// ---------------------------------------------------------------------------
// R3: MFMA gemm1. One wave = 16-node tile. A-frag = W^T in registers as
// fp16 hi/lo split pairs. B-frag = 32B of the lane's x row per K-step.
// C = P^T: lane(quad,n) holds features quad*4..+3 of node n -> 8B stores.
__global__ __launch_bounds__(256, 4) void gemm1_kernel(
    const float* __restrict__ x, const float* __restrict__ wl,
    const float* __restrict__ wr, __half* __restrict__ p,
    __half* __restrict__ q, int N, int ntiles)
{
    int lane   = threadIdx.x & 63;
    int wave   = (blockIdx.x * blockDim.x + threadIdx.x) >> 6;
    int nwaves = (gridDim.x * blockDim.x) >> 6;

    int m  = lane & 15;   // A row (feature) / B col (node) / C col (node)
    int qd = lane >> 4;   // quad

    half8 wlh[4], wll[4], wrh[4], wrl[4];
    #pragma unroll
    for (int kk = 0; kk < 4; ++kk) {
        #pragma unroll
        for (int j = 0; j < 8; ++j) {
            int k = kk * 32 + qd * 8 + j;
            float a = wl[k * HID + m];
            _Float16 ah = (_Float16)a;
            wlh[kk][j] = ah;
            wll[kk][j] = (_Float16)(a - (float)ah);
            float b = wr[k * HID + m];
            _Float16 bh = (_Float16)b;
            wrh[kk][j] = bh;
            wrl[kk][j] = (_Float16)(b - (float)bh);
        }
    }

    for (int t = wave; t < ntiles; t += nwaves) {
        int node = t * 16 + m;
        int nc   = node < N ? node : N - 1;
        const float4* xr = (const float4*)(x + (size_t)nc * NF);

        floatx4 accl = {0.f, 0.f, 0.f, 0.f};
        floatx4 accr = {0.f, 0.f, 0.f, 0.f};

        #pragma unroll
        for (int kk = 0; kk < 4; ++kk) {
            float4 v0 = xr[kk * 8 + qd * 2 + 0];
            float4 v1 = xr[kk * 8 + qd * 2 + 1];
            float xs[8] = {v0.x, v0.y, v0.z, v0.w, v1.x, v1.y, v1.z, v1.w};
            half8 xh, xlo;
            #pragma unroll
            for (int j = 0; j < 8; ++j) {
                _Float16 hh = (_Float16)xs[j];
                xh[j]  = hh;
                xlo[j] = (_Float16)(xs[j] - (float)hh);
            }
            accl = __builtin_amdgcn_mfma_f32_16x16x32_f16(wlh[kk], xh,  accl, 0, 0, 0);
            accr = __builtin_amdgcn_mfma_f32_16x16x32_f16(wrh[kk], xh,  accr, 0, 0, 0);
            accl = __builtin_amdgcn_mfma_f32_16x16x32_f16(wll[kk], xh,  accl, 0, 0, 0);
            accr = __builtin_amdgcn_mfma_f32_16x16x32_f16(wrl[kk], xh,  accr, 0, 0, 0);
            accl = __builtin_amdgcn_mfma_f32_16x16x32_f16(wlh[kk], xlo, accl, 0, 0, 0);
            accr = __builtin_amdgcn_mfma_f32_16x16x32_f16(wrh[kk], xlo, accr, 0, 0, 0);
        }

        if (node < N) {
            float2 pv, qv;
            *(__half2*)&pv.x = __floats2half2_rn(accl[0], accl[1]);
            *(__half2*)&pv.y = __floats2half2_rn(accl[2], accl[3]);
            *(__half2*)&qv.x = __floats2half2_rn(accr[0], accr[1]);
            *(__half2*)&qv.y = __floats2half2_rn(accr[2], accr[3]);
            *(float2*)(p + (size_t)node * HID + qd * 4) = pv;
            *(float2*)(q + (size_t)node * HID + qd * 4) = qv;
        }
    }
}

// ---------------------------------------------------------------------------
// Accumulate helper: 8 features from a 16B half-row.
#define ACC8(raw)                                                      \
    {                                                                  \
        float2 v0 = __half22float2(*(const __half2*)&(raw).x);         \
        float2 v1 = __half22float2(*(const __half2*)&(raw).y);         \
        float2 v2 = __half22float2(*(const __half2*)&(raw).z);         \
        float2 v3 = __half22float2(*(const __half2*)&(raw).w);         \
        a0 += v0.x; a1 += v0.y; a2 += v1.x; a3 += v1.y;                \
        a4 += v2.x; a5 += v2.y; a6 += v3.x; a7 += v3.y;                \
    }

// 8-deep unrolled gather-accumulate over sorted[st..st+n) from p rows.
#define GATHER_LOOP(p_, sorted_, st_, n_, fb_)                         \
    {                                                                  \
        int i = 0;                                                     \
        for (; i + 8 <= (n_); i += 8) {                                \
            int s0 = (sorted_)[(st_) + i + 0], s1 = (sorted_)[(st_) + i + 1]; \
            int s2 = (sorted_)[(st_) + i + 2], s3 = (sorted_)[(st_) + i + 3]; \
            int s4 = (sorted_)[(st_) + i + 4], s5 = (sorted_)[(st_) + i + 5]; \
            int s6 = (sorted_)[(st_) + i + 6], s7 = (sorted_)[(st_) + i + 7]; \
            float4 r0 = *(const float4*)((p_) + (size_t)s0 * HID + (fb_)); \
            float4 r1 = *(const float4*)((p_) + (size_t)s1 * HID + (fb_)); \
            float4 r2 = *(const float4*)((p_) + (size_t)s2 * HID + (fb_)); \
            float4 r3 = *(const float4*)((p_) + (size_t)s3 * HID + (fb_)); \
            float4 r4 = *(const float4*)((p_) + (size_t)s4 * HID + (fb_)); \
            float4 r5 = *(const float4*)((p_) + (size_t)s5 * HID + (fb_)); \
            float4 r6 = *(const float4*)((p_) + (size_t)s6 * HID + (fb_)); \
            float4 r7 = *(const float4*)((p_) + (size_t)s7 * HID + (fb_)); \
            ACC8(r0); ACC8(r1); ACC8(r2); ACC8(r3);                    \
            ACC8(r4); ACC8(r5); ACC8(r6); ACC8(r7);                    \
        }                                                              \
        for (; i < (n_); ++i) {                                        \
            int s = (sorted_)[(st_) + i];                              \
            float4 raw = *(const float4*)((p_) + (size_t)s * HID + (fb_)); \
            ACC8(raw);                                                 \
        }                                                              \
    }

// Shared epilogue: mean + bias + root + relu -> h
__device__ __forceinline__ void agg_epilogue(
    float a0, float a1, float a2, float a3,
    float a4, float a5, float a6, float a7,
    int n_cnt, int fb, int node,
    const __half* __restrict__ q, const float* __restrict__ b,
    __half* __restrict__ h)
{
    float inv = 1.f / fmaxf((float)n_cnt, 1.f);
    float4 qraw = *(const float4*)(q + (size_t)node * HID + fb);
    float2 q0 = __half22float2(*(const __half2*)&qraw.x);
    float2 q1 = __half22float2(*(const __half2*)&qraw.y);
    float2 q2 = __half22float2(*(const __half2*)&qraw.z);
    float2 q3 = __half22float2(*(const __half2*)&qraw.w);

    __half2 r0 = __floats2half2_rn(fmaxf(a0*inv + b[fb+0] + q0.x, 0.f),
                                   fmaxf(a1*inv + b[fb+1] + q0.y, 0.f));
    __half2 r1 = __floats2half2_rn(fmaxf(a2*inv + b[fb+2] + q1.x, 0.f),
                                   fmaxf(a3*inv + b[fb+3] + q1.y, 0.f));
    __half2 r2 = __floats2half2_rn(fmaxf(a4*inv + b[fb+4] + q2.x, 0.f),
                                   fmaxf(a5*inv + b[fb+5] + q2.y, 0.f));
    __half2 r3 = __floats2half2_rn(fmaxf(a6*inv + b[fb+6] + q3.x, 0.f),
                                   fmaxf(a7*inv + b[fb+7] + q3.y, 0.f));
    float4 res;
    *(__half2*)&res.x = r0; *(__half2*)&res.y = r1;
    *(__half2*)&res.z = r2; *(__half2*)&res.w = r3;
    *(float4*)(h + (size_t)node * HID + fb) = res;
}

// ---------------------------------------------------------------------------
// R5: agg#1 FUSED with gemm2. In-LDS counting sort + CSR persist + gather,
// then h1 = relu(mean+b1+q1) stays in registers/LDS (f32, never written to
// global) and the 16x16 W2l/W2r matvec runs in the epilogue, writing
// p2 -> C16, q2 -> D16 (fresh buffers: in-place would race with
// cross-bucket p1 gathers).
__global__ __launch_bounds__(256) void bucket_agg1_fused_kernel(
    const int* __restrict__ cursor, const int* __restrict__ recs,
    const int* __restrict__ ovf_cnt, const int2* __restrict__ ovf,
    const __half* __restrict__ p, const __half* __restrict__ q,
    const float* __restrict__ b1,
    const float* __restrict__ w2l, const float* __restrict__ w2r,
    __half* __restrict__ p2, __half* __restrict__ q2, int N, int K,
    int* __restrict__ g_sorted, int* __restrict__ g_cnt,
    int* __restrict__ g_off)
{
    __shared__ int sorted[SMAX];
    __shared__ int cnt[NPB];
    __shared__ int off[NPB];
    __shared__ int cur[NPB];
    __shared__ int scan[NPB];
    __shared__ int s_ovf;

    int bkt = blockIdx.x;
    int tid = threadIdx.x;

    if (tid < NPB) cnt[tid] = 0;
    if (tid == 0) { int v = *ovf_cnt; s_ovf = v < OVF_CAP ? v : OVF_CAP; }
    __syncthreads();

    for (int xcd = 0; xcd < NXCD; ++xcd) {
        int cell = xcd * K + bkt;
        int len = cursor[cell]; if (len > CAP) len = CAP;
        const int* cr = recs + (size_t)cell * CAP;
        for (int r = tid; r < len; r += 256)
            atomicAdd(&cnt[((unsigned)cr[r]) >> 17], 1);
    }
    if (s_ovf > 0) {
        for (int r = tid; r < s_ovf; r += 256) {
            int2 od = ovf[r];
            if ((od.x >> 7) == bkt) atomicAdd(&cnt[od.x & 127], 1);
        }
    }
    __syncthreads();

    if (tid < NPB) scan[tid] = cnt[tid];
    __syncthreads();
    for (int o = 1; o < NPB; o <<= 1) {
        int v = 0;
        if (tid < NPB && tid >= o) v = scan[tid - o];
        __syncthreads();
        if (tid < NPB) scan[tid] += v;
        __syncthreads();
    }
    if (tid < NPB) { int e = scan[tid] - cnt[tid]; off[tid] = e; cur[tid] = e; }
    __syncthreads();

    for (int xcd = 0; xcd < NXCD; ++xcd) {
        int cell = xcd * K + bkt;
        int len = cursor[cell]; if (len > CAP) len = CAP;
        const int* cr = recs + (size_t)cell * CAP;
        for (int r = tid; r < len; r += 256) {
            int rec = cr[r];
            int slot = atomicAdd(&cur[((unsigned)rec) >> 17], 1);
            if (slot < SMAX) sorted[slot] = rec & 0x1FFFF;
        }
    }
    if (s_ovf > 0) {
        for (int r = tid; r < s_ovf; r += 256) {
            int2 od = ovf[r];
            if ((od.x >> 7) == bkt) {
                int slot = atomicAdd(&cur[od.x & 127], 1);
                if (slot < SMAX) sorted[slot] = od.y;
            }
        }
    }
    __syncthreads();

    // Persist CSR for the second aggregation pass.
    int total = off[NPB - 1] + cnt[NPB - 1];
    if (total > SMAX) total = SMAX;
    int* gs = g_sorted + (size_t)bkt * SMAX;
    for (int i = tid; i < total; i += 256) gs[i] = sorted[i];
    if (tid < NPB) {
        g_cnt[bkt * NPB + tid] = cnt[tid];
        g_off[bkt * NPB + tid] = off[tid];
    }

    int dl   = tid >> 1;
    int half = tid & 1;
    int node = (bkt << 7) + dl;
    bool act = node < N;                // no early return: barriers below

    int st = 0, nn = 0, fb = half * 8;
    if (act) {
        st = off[dl];
        nn = cnt[dl];
        if (st > SMAX) st = SMAX;
        if (st + nn > SMAX) nn = SMAX - st;
    }

    float a0 = 0.f, a1 = 0.f, a2 = 0.f, a3 = 0.f,
          a4 = 0.f, a5 = 0.f, a6 = 0.f, a7 = 0.f;
    GATHER_LOOP(p, sorted, st, nn, fb);

    // h1 in f32 registers (mean + bias + root + relu)
    float h1v[8];
    if (act) {
        float inv = 1.f / fmaxf((float)cnt[dl], 1.f);
        float4 qraw = *(const float4*)(q + (size_t)node * HID + fb);
        float2 q0 = __half22float2(*(const __half2*)&qraw.x);
        float2 q1 = __half22float2(*(const __half2*)&qraw.y);
        float2 q2v = __half22float2(*(const __half2*)&qraw.z);
        float2 q3 = __half22float2(*(const __half2*)&qraw.w);
        h1v[0] = fmaxf(a0*inv + b1[fb+0] + q0.x, 0.f);
        h1v[1] = fmaxf(a1*inv + b1[fb+1] + q0.y, 0.f);
        h1v[2] = fmaxf(a2*inv + b1[fb+2] + q1.x, 0.f);
        h1v[3] = fmaxf(a3*inv + b1[fb+3] + q1.y, 0.f);
        h1v[4] = fmaxf(a4*inv + b1[fb+4] + q2v.x, 0.f);
        h1v[5] = fmaxf(a5*inv + b1[fb+5] + q2v.y, 0.f);
        h1v[6] = fmaxf(a6*inv + b1[fb+6] + q3.x, 0.f);
        h1v[7] = fmaxf(a7*inv + b1[fb+7] + q3.y, 0.f);
    }
    __syncthreads();                    // all sorted[] reads complete

    // Stage h1 rows in LDS (alias sorted; stride 17 -> conflict-free)
    float* hl = (float*)sorted;         // needs 128*17 = 2176 floats < SMAX
    if (act) {
        #pragma unroll
        for (int j = 0; j < 8; ++j) hl[dl * 17 + fb + j] = h1v[j];
    }
    __syncthreads();

    if (act) {
        float hv[16];
        #pragma unroll
        for (int k = 0; k < HID; ++k) hv[k] = hl[dl * 17 + k];

        float accl[8], accr[8];
        #pragma unroll
        for (int f = 0; f < 8; ++f) { accl[f] = 0.f; accr[f] = 0.f; }
        #pragma unroll
        for (int k = 0; k < HID; ++k) {
            float hs = hv[k];
            #pragma unroll
            for (int f = 0; f < 8; ++f) {
                accl[f] = fmaf(hs, w2l[k * HID + fb + f], accl[f]);
                accr[f] = fmaf(hs, w2r[k * HID + fb + f], accr[f]);
            }
        }

        __half2 po[4], qo[4];
        #pragma unroll
        for (int f = 0; f < 4; ++f) {
            po[f] = __floats2half2_rn(accl[2*f], accl[2*f+1]);
            qo[f] = __floats2half2_rn(accr[2*f], accr[2*f+1]);
        }
        *(float4*)(p2 + (size_t)node * HID + fb) = *(float4*)&po[0];
        *(float4*)(q2 + (size_t)node * HID + fb) = *(float4*)&qo[0];
    }
}

// ---------------------------------------------------------------------------
// R5: agg#2 — sort-free. Loads persisted CSR into LDS, 8-way unrolled
// gather-accumulate. h may alias q (own-bucket rows only, read-then-write).
__global__ __launch_bounds__(256) void bucket_agg_reuse_kernel(
    const int* __restrict__ g_sorted, const int* __restrict__ g_cnt,
    const int* __restrict__ g_off,
    const __half* __restrict__ p, const __half* __restrict__ q,
    const float* __restrict__ b, __half* __restrict__ h, int N, int K)
{
    __shared__ int sorted[SMAX];
    __shared__ int cnt[NPB];
    __shared__ int off[NPB];

    int bkt = blockIdx.x;
    int tid = threadIdx.x;

    if (tid < NPB) {
        cnt[tid] = g_cnt[bkt * NPB + tid];
        off[tid] = g_off[bkt * NPB + tid];
    }
    __syncthreads();

    int total = off[NPB - 1] + cnt[NPB - 1];
    if (total > SMAX) total = SMAX;
    const int* gs = g_sorted + (size_t)bkt * SMAX;
    for (int i = tid; i < total; i += 256) sorted[i] = gs[i];
    __syncthreads();

    int dl   = tid >> 1;
    int half = tid & 1;
    int node = (bkt << 7) + dl;
    if (node >= N) return;

    int st = off[dl];
    int n  = cnt[dl];
    if (st > SMAX) st = SMAX;
    if (st + n > SMAX) n = SMAX - st;
    int fb = half * 8;

    float a0 = 0.f, a1 = 0.f, a2 = 0.f, a3 = 0.f,
          a4 = 0.f, a5 = 0.f, a6 = 0.f, a7 = 0.f;
    GATHER_LOOP(p, sorted, st, n, fb);

    agg_epilogue(a0, a1, a2, a3, a4, a5, a6, a7, cnt[dl], fb, node, q, b, h);
}

// ---------------------------------------------------------------------------
// MFMA edge MLP, transposed form. fc2 reduction via a SECOND MFMA
// (16x16x16): the first MFMA's C layout (lane(q,n) holds Z[k=q*4+r][edge n])
// is exactly the K=16 B-fragment layout; A = W2^T zero-padded to 16 rows.
// Lanes q==0 get both class logits in acc2[0..1] and store coalesced float2.
__global__ __launch_bounds__(256) void edge_mlp_mfma_kernel(
    const int* __restrict__ src, const int* __restrict__ dst,
    const __half* __restrict__ h,
    const float* __restrict__ fc1w, const float* __restrict__ fc1b,
    const float* __restrict__ fc2w, const float* __restrict__ fc2b,
    float* __restrict__ out, int E, int ntiles)
{
    int lane   = threadIdx.x & 63;
    int wave   = (blockIdx.x * blockDim.x + threadIdx.x) >> 6;
    int nwaves = (gridDim.x * blockDim.x) >> 6;

    int n = lane & 15;      // edge within tile (B col, C col); also A row
    int q = lane >> 4;      // quad

    // fc1 A-fragment = W1^T: A[m=lane&15][k=q*8+j] = fc1w[(q*8+j)*16 + m]
    half8 wfrag;
    #pragma unroll
    for (int j = 0; j < 8; ++j)
        wfrag[j] = (_Float16)fc1w[(q * 8 + j) * 16 + n];

    // fc2 A-fragment (K=16): A[m=lane&15][k=q*4+j] = fc2w[(q*4+j)*2 + m], m<2
    half4 w2frag;
    #pragma unroll
    for (int j = 0; j < 4; ++j)
        w2frag[j] = (n < 2) ? (_Float16)fc2w[(q * 4 + j) * 2 + n]
                            : (_Float16)0.f;

    // fc1 bias for this lane's 4 z-rows (k = q*4+r)
    float bias1[4];
    #pragma unroll
    for (int r = 0; r < 4; ++r) bias1[r] = fc1b[q * 4 + r];
    float bb0 = fc2b[0], bb1 = fc2b[1];

    const int* tp = (q < 2) ? src : dst;
    int hoff = (q & 1) * 8;

    for (int t = wave; t < ntiles; t += nwaves) {
        int e   = t * 16 + n;
        int e_c = e < E ? e : E - 1;
        int idx = tp[e_c];
        half8 xf = *(const half8*)(h + (size_t)idx * HID + hoff);

        floatx4 acc = {0.f, 0.f, 0.f, 0.f};
        acc = __builtin_amdgcn_mfma_f32_16x16x32_f16(wfrag, xf, acc, 0, 0, 0);

        // z = relu(acc + b1) -> fp16 B-fragment for the fc2 MFMA
        half4 z;
        #pragma unroll
        for (int r = 0; r < 4; ++r)
            z[r] = (_Float16)fmaxf(acc[r] + bias1[r], 0.f);

        floatx4 acc2 = {0.f, 0.f, 0.f, 0.f};
        acc2 = __builtin_amdgcn_mfma_f32_16x16x16f16(w2frag, z, acc2, 0, 0, 0);

        if (q == 0) {
            int eo = t * 16 + n;
            if (eo < E) {
                float a  = acc2[0] + bb0;
                float c  = acc2[1] + bb1;
                float mx = fmaxf(a, c);
                float lse = mx + __logf(__expf(a - mx) + __expf(c - mx));
                ((float2*)out)[eo] = make_float2(a - lse, c - lse);
            }
        }
    }
}

// ---------------------------------------------------------------------------
extern "C" void kernel_launch(void* const* d_in, const int* in_sizes, int n_in,
                              void* d_out, int out_size, void* d_ws, size_t ws_size,
                              hipStream_t stream)
{
    const float* x    = (const float*)d_in[0];
    const int*   ei   = (const int*)  d_in[1];
    const float* w1l  = (const float*)d_in[2];
    const float* b1l  = (const float*)d_in[3];
    const float* w1r  = (const float*)d_in[4];
    const float* w2l  = (const float*)d_in[5];
    const float* b2l  = (const float*)d_in[6];
    const float* w2r  = (const float*)d_in[7];
    const float* fc1w = (const float*)d_in[8];
    const float* fc1b = (const float*)d_in[9];
    const float* fc2w = (const float*)d_in[10];
    const float* fc2b = (const float*)d_in[11];
    float* out = (float*)d_out;

    int N = in_sizes[0] / NF;
    int E = in_sizes[1] / 2;
    const int* src = ei;
    const int* dst = ei + E;

    int K = (N + NPB - 1) / NPB;   // 782 buckets (<= KMAX)

    // ws: A16|B16|C16|D16 | recs | cursor | ovf_cnt | ovf | g_sorted|g_cnt|g_off
    __half* A16      = (__half*)d_ws;            // p1
    __half* B16      = A16 + (size_t)N * HID;    // q1
    __half* C16      = B16 + (size_t)N * HID;    // p2
    __half* D16      = C16 + (size_t)N * HID;    // q2 -> h2 (in-place)
    int*    recs     = (int*)(D16 + (size_t)N * HID);
    int*    cursor   = recs + (size_t)NXCD * K * CAP;
    int*    ovfcnt   = cursor + (size_t)NXCD * K;
    int2*   ovf      = (int2*)(ovfcnt + 2);
    int*    g_sorted = (int*)(ovf + OVF_CAP);
    int*    g_cnt    = g_sorted + (size_t)K * SMAX;
    int*    g_off    = g_cnt + (size_t)K * NPB;

    int ncur = NXCD * K + 1;

    zero_kernel<<<(ncur + 255) / 256, 256, 0, stream>>>(cursor, ncur);
    scatter_bin_kernel<<<(E + CH - 1) / CH, 256, 0, stream>>>(src, dst, cursor, recs,
                                                              ovfcnt, ovf, E, K);

    int ntiles_n = (N + 15) / 16;            // 6250
    int gemm_blocks = (ntiles_n + 7) / 8;    // 2 tiles per wave, balanced

    gemm1_kernel<<<gemm_blocks, 256, 0, stream>>>(x, w1l, w1r, A16, B16, N, ntiles_n);

    // agg#1 fused with gemm2: h1 never hits global; writes p2->C16, q2->D16
    bucket_agg1_fused_kernel<<<K, 256, 0, stream>>>(cursor, recs, ovfcnt, ovf,
                                                    A16, B16, b1l, w2l, w2r,
                                                    C16, D16, N, K,
                                                    g_sorted, g_cnt, g_off);

    // agg#2: h2 = relu(mean(p2)+b2+q2), in-place over D16
    bucket_agg_reuse_kernel<<<K, 256, 0, stream>>>(g_sorted, g_cnt, g_off,
                                                   C16, D16, b2l, D16, N, K);

    int ntiles = (E + 15) / 16;
    edge_mlp_mfma_kernel<<<2048, 256, 0, stream>>>(src, dst, D16, fc1w, fc1b,
                                                   fc2w, fc2b, out, E, ntiles);
}